// Round 14
// baseline (659.868 us; speedup 1.0000x reference)
//
#include <hip/hip_runtime.h>
#include <hip/hip_bf16.h>
#include <math.h>

#define LN_EPS 1e-5f

constexpr int Bb = 8, Ss = 2048, Ee = 512, Ll = 6, Ff = 2048, Cc = 10;
constexpr int Nn = Bb * Ss;  // 16384 rows

typedef __attribute__((ext_vector_type(8))) short short8v;
typedef __attribute__((ext_vector_type(4))) float f32x4;

__device__ __forceinline__ unsigned short f2bf(float f) {
    unsigned int b = __float_as_uint(f);
    b += 0x7FFFu + ((b >> 16) & 1u);   // RNE
    return (unsigned short)(b >> 16);
}

__device__ __forceinline__ float bf2f(unsigned short u) {
    return __uint_as_float((unsigned int)u << 16);
}

__device__ __forceinline__ float fastcos(float x) {
    float r = x * 0.15915494309189535f;     // radians -> revolutions
    r = __builtin_amdgcn_fractf(r);         // reduce to [0,1)
    return __builtin_amdgcn_cosf(r);        // v_cos_f32
}

// async global->LDS, 16B per lane. LDS dest = wave-uniform base + lane*16.
__device__ __forceinline__ void gload16(const void* g, void* lds) {
    __builtin_amdgcn_global_load_lds(
        (__attribute__((address_space(1))) void*)(g),
        (__attribute__((address_space(3))) void*)(lds),
        16, 0, 0);
}

// ---------------- positional encoding table ----------------
__global__ void pe_kernel(float* __restrict__ pe) {
    int p = blockIdx.x * blockDim.x + threadIdx.x;
    int total = Ss * (Ee / 2);
    if (p >= total) return;
    int s = p / (Ee / 2);
    int i = p % (Ee / 2);
    float div = expf(float(2 * i) * (-logf(10000.0f) / float(Ee)));
    float ang = float(s) * div;
    pe[s * Ee + 2 * i]     = sinf(ang);
    pe[s * Ee + 2 * i + 1] = cosf(ang);
}

// ---------------- embedding + PE (+ Acos for layer 0) ----------------
__global__ void embed_kernel(const int* __restrict__ tokens,
                             const float* __restrict__ emb,
                             const float* __restrict__ pe,
                             const float* __restrict__ theta0,
                             float* __restrict__ x,
                             unsigned short* __restrict__ acos) {
    int idx = blockIdx.x * blockDim.x + threadIdx.x;
    int total = Nn * Ee / 4;
    if (idx >= total) return;
    int n  = idx / (Ee / 4);
    int e4 = idx % (Ee / 4);
    int tok = tokens[n];
    int s = n % Ss;
    f32x4 a = *(const f32x4*)(emb + (size_t)tok * Ee + e4 * 4);
    f32x4 p = *(const f32x4*)(pe + (size_t)s * Ee + e4 * 4);
    f32x4 o = a + p;
    *(f32x4*)(x + (size_t)n * Ee + e4 * 4) = o;
    f32x4 t = *(const f32x4*)(theta0 + e4 * 4);
    ushort4 c;
    c.x = f2bf(fastcos(o.x + t.x));
    c.y = f2bf(fastcos(o.y + t.y));
    c.z = f2bf(fastcos(o.z + t.z));
    c.w = f2bf(fastcos(o.w + t.w));
    *(ushort4*)(acos + (size_t)n * Ee + e4 * 4) = c;
}

// ---------------- fp32 -> bf16 weight conversion ----------------
__global__ void cvt_bf16(const float* __restrict__ in,
                         unsigned short* __restrict__ out, int n4) {
    int i = blockIdx.x * blockDim.x + threadIdx.x;
    if (i >= n4) return;
    f32x4 v = *(const f32x4*)(in + (size_t)i * 4);
    ushort4 o;
    o.x = f2bf(v.x); o.y = f2bf(v.y); o.z = f2bf(v.z); o.w = f2bf(v.w);
    *(ushort4*)(out + (size_t)i * 4) = o;
}

// ---------------- H = bf16(relu(z @ W1^T + b1)) ----------------
__global__ __launch_bounds__(256) void h_kernel(const float* __restrict__ z,
                                                const float* __restrict__ W1,
                                                const float* __restrict__ b1,
                                                unsigned short* __restrict__ H) {
    __shared__ unsigned short hls[8 * Ff];
    const int t  = threadIdx.x;
    const int m0 = blockIdx.x * 8;
    f32x4 zr[8];
#pragma unroll
    for (int r = 0; r < 8; ++r)
        zr[r] = *(const f32x4*)(z + (size_t)(m0 + r) * 4);
#pragma unroll
    for (int j = 0; j < 8; ++j) {
        const int f = t + 256 * j;
        f32x4 w = *(const f32x4*)(W1 + (size_t)f * 4);  // coalesced
        float bb = b1[f];                               // coalesced
#pragma unroll
        for (int r = 0; r < 8; ++r) {
            float v = zr[r].x * w.x + zr[r].y * w.y + zr[r].z * w.z +
                      zr[r].w * w.w + bb;
            hls[r * Ff + f] = f2bf(fmaxf(v, 0.f));
        }
    }
    __syncthreads();
#pragma unroll
    for (int j = 0; j < 8; ++j) {
        const int idx = (j * 256 + t) * 8;   // ushort index, 16B per thread
        *(short8v*)(H + (size_t)m0 * Ff + idx) = *(const short8v*)(&hls[idx]);
    }
}

// =========== bf16 GEMM: Coutb = bf16(A @ Wb^T + bias + xres) ===========
// Round-13 structure (best: 41us): 128x128 tile, BK=64, 8 waves, depth-2
// prefetch over 2 LDS buffers via reg-hoisted fragments. Output now bf16
// (tmp round-trip halved). Staging/read layout unchanged (0 conflicts).
__global__ __launch_bounds__(512, 4) void gemm_bf16(
    const unsigned short* __restrict__ A,
    const unsigned short* __restrict__ Wb,
    const float* __restrict__ bias,
    const float* __restrict__ xres,
    unsigned short* __restrict__ Coutb,
    int K) {
    __shared__ unsigned short As[2][128 * 64];
    __shared__ unsigned short Bs[2][128 * 64];
    const int tid  = threadIdx.x;
    const int lane = tid & 63;
    const int wid  = tid >> 6;     // 0..7
    const int wr   = wid >> 2;     // 0..1 (64-row band)
    const int wc   = wid & 3;      // 0..3 (32-col band)
    const int wg   = blockIdx.x;
    const int sw   = (wg & 7) * 64 + (wg >> 3);
    const int row0 = (sw >> 2) * 128;
    const int col0 = (sw & 3) * 128;
    const int srow   = lane >> 3;
    const int pchunk = lane & 7;

    f32x4 acc[4][2];
#pragma unroll
    for (int m = 0; m < 4; m++)
#pragma unroll
        for (int n = 0; n < 2; n++) acc[m][n] = {0.f, 0.f, 0.f, 0.f};

    const int NT = K >> 6;

    auto STAGE = [&](int buf, int k0) {
#pragma unroll
        for (int i = 0; i < 2; ++i) {
            const int s   = wid * 2 + i;
            const int row = s * 8 + srow;
            const int lc  = pchunk ^ (row & 7);
            gload16(A  + (size_t)(row0 + row) * K + k0 + lc * 8, &As[buf][s * 512]);
        }
#pragma unroll
        for (int i = 0; i < 2; ++i) {
            const int s   = wid * 2 + i;
            const int row = s * 8 + srow;
            const int lc  = pchunk ^ (row & 7);
            gload16(Wb + (size_t)(col0 + row) * K + k0 + lc * 8, &Bs[buf][s * 512]);
        }
    };

    STAGE(0, 0);
    if (NT > 1) STAGE(1, 64);
    for (int kt = 0; kt < NT; ++kt) {
        const int b = kt & 1;
        if (kt + 1 < NT) {
            asm volatile("s_waitcnt vmcnt(4)" ::: "memory");
        } else {
            asm volatile("s_waitcnt vmcnt(0)" ::: "memory");
        }
        __builtin_amdgcn_s_barrier();
        asm volatile("" ::: "memory");
        short8v aF[2][4], bF[2][2];
#pragma unroll
        for (int ks = 0; ks < 2; ks++) {
            const int k8 = ks * 4 + (lane >> 4);
#pragma unroll
            for (int m = 0; m < 4; m++) {
                const int row = wr * 64 + m * 16 + (lane & 15);
                aF[ks][m] = *(const short8v*)(&As[b][row * 64 + ((k8 ^ (row & 7)) * 8)]);
            }
#pragma unroll
            for (int n = 0; n < 2; n++) {
                const int row = wc * 32 + n * 16 + (lane & 15);
                bF[ks][n] = *(const short8v*)(&Bs[b][row * 64 + ((k8 ^ (row & 7)) * 8)]);
            }
        }
        asm volatile("s_waitcnt lgkmcnt(0)" ::: "memory");
        __builtin_amdgcn_s_barrier();
        asm volatile("" ::: "memory");
        if (kt + 2 < NT) STAGE(b, (kt + 2) << 6);
#pragma unroll
        for (int ks = 0; ks < 2; ks++)
#pragma unroll
            for (int m = 0; m < 4; m++)
#pragma unroll
                for (int n = 0; n < 2; n++)
                    acc[m][n] = __builtin_amdgcn_mfma_f32_16x16x32_bf16(
                        aF[ks][m], bF[ks][n], acc[m][n], 0, 0, 0);
    }

#pragma unroll
    for (int m = 0; m < 4; m++) {
#pragma unroll
        for (int n = 0; n < 2; n++) {
            int colg = col0 + wc * 32 + n * 16 + (lane & 15);
            float bv = bias[colg];
#pragma unroll
            for (int j = 0; j < 4; j++) {
                int rowg = row0 + wr * 64 + m * 16 + ((lane >> 4) * 4) + j;
                size_t off = (size_t)rowg * 512 + colg;
                Coutb[off] = f2bf(acc[m][n][j] + bv + xres[off]);
            }
        }
    }
}

// ------- LN: 2 rows per wave (8 rows/block) on bf16 tmp -> fp32 x -------
__global__ __launch_bounds__(256) void ln_fused(
    const unsigned short* __restrict__ tmp, float* __restrict__ x,
    const float* __restrict__ g, const float* __restrict__ b,
    const float* __restrict__ phi, float* __restrict__ z,
    const float* __restrict__ theta, unsigned short* __restrict__ acos) {
    const int wv   = threadIdx.x >> 6;
    const int lane = threadIdx.x & 63;
    const int row0 = blockIdx.x * 8 + wv * 2;  // this wave: row0, row0+1

    f32x4 g0 = *(const f32x4*)(g + lane * 4);
    f32x4 b0 = *(const f32x4*)(b + lane * 4);
    f32x4 g1 = *(const f32x4*)(g + 256 + lane * 4);
    f32x4 b1v = *(const f32x4*)(b + 256 + lane * 4);

    // load both rows (bf16), convert
    f32x4 vA0, vA1, vB0, vB1;
    {
        const unsigned short* t0 = tmp + (size_t)row0 * Ee;
        const unsigned short* t1 = tmp + (size_t)(row0 + 1) * Ee;
        ushort4 a0 = *(const ushort4*)(t0 + lane * 4);
        ushort4 a1 = *(const ushort4*)(t0 + 256 + lane * 4);
        ushort4 c0 = *(const ushort4*)(t1 + lane * 4);
        ushort4 c1 = *(const ushort4*)(t1 + 256 + lane * 4);
        vA0 = {bf2f(a0.x), bf2f(a0.y), bf2f(a0.z), bf2f(a0.w)};
        vA1 = {bf2f(a1.x), bf2f(a1.y), bf2f(a1.z), bf2f(a1.w)};
        vB0 = {bf2f(c0.x), bf2f(c0.y), bf2f(c0.z), bf2f(c0.w)};
        vB1 = {bf2f(c1.x), bf2f(c1.y), bf2f(c1.z), bf2f(c1.w)};
    }
    float s0 = vA0.x + vA0.y + vA0.z + vA0.w + vA1.x + vA1.y + vA1.z + vA1.w;
    float s1 = vB0.x + vB0.y + vB0.z + vB0.w + vB1.x + vB1.y + vB1.z + vB1.w;
#pragma unroll
    for (int o = 32; o; o >>= 1) {
        s0 += __shfl_xor(s0, o);
        s1 += __shfl_xor(s1, o);
    }
    float mu0 = s0 * (1.f / 512.f), mu1 = s1 * (1.f / 512.f);
    f32x4 dA0 = {vA0.x - mu0, vA0.y - mu0, vA0.z - mu0, vA0.w - mu0};
    f32x4 dA1 = {vA1.x - mu0, vA1.y - mu0, vA1.z - mu0, vA1.w - mu0};
    f32x4 dB0 = {vB0.x - mu1, vB0.y - mu1, vB0.z - mu1, vB0.w - mu1};
    f32x4 dB1 = {vB1.x - mu1, vB1.y - mu1, vB1.z - mu1, vB1.w - mu1};
    float q0 = dA0.x * dA0.x + dA0.y * dA0.y + dA0.z * dA0.z + dA0.w * dA0.w +
               dA1.x * dA1.x + dA1.y * dA1.y + dA1.z * dA1.z + dA1.w * dA1.w;
    float q1 = dB0.x * dB0.x + dB0.y * dB0.y + dB0.z * dB0.z + dB0.w * dB0.w +
               dB1.x * dB1.x + dB1.y * dB1.y + dB1.z * dB1.z + dB1.w * dB1.w;
#pragma unroll
    for (int o = 32; o; o >>= 1) {
        q0 += __shfl_xor(q0, o);
        q1 += __shfl_xor(q1, o);
    }
    float rs0 = rsqrtf(q0 * (1.f / 512.f) + LN_EPS);
    float rs1 = rsqrtf(q1 * (1.f / 512.f) + LN_EPS);

    f32x4 oA0 = {dA0.x * rs0 * g0.x + b0.x, dA0.y * rs0 * g0.y + b0.y,
                 dA0.z * rs0 * g0.z + b0.z, dA0.w * rs0 * g0.w + b0.w};
    f32x4 oA1 = {dA1.x * rs0 * g1.x + b1v.x, dA1.y * rs0 * g1.y + b1v.y,
                 dA1.z * rs0 * g1.z + b1v.z, dA1.w * rs0 * g1.w + b1v.w};
    f32x4 oB0 = {dB0.x * rs1 * g0.x + b0.x, dB0.y * rs1 * g0.y + b0.y,
                 dB0.z * rs1 * g0.z + b0.z, dB0.w * rs1 * g0.w + b0.w};
    f32x4 oB1 = {dB1.x * rs1 * g1.x + b1v.x, dB1.y * rs1 * g1.y + b1v.y,
                 dB1.z * rs1 * g1.z + b1v.z, dB1.w * rs1 * g1.w + b1v.w};
    *(f32x4*)(x + (size_t)row0 * Ee + lane * 4) = oA0;
    *(f32x4*)(x + (size_t)row0 * Ee + 256 + lane * 4) = oA1;
    *(f32x4*)(x + (size_t)(row0 + 1) * Ee + lane * 4) = oB0;
    *(f32x4*)(x + (size_t)(row0 + 1) * Ee + 256 + lane * 4) = oB1;
    if (z != nullptr && lane == 0) {
        float c0p = fastcos(phi[0]), c1p = fastcos(phi[1]);
        float c2p = fastcos(phi[2]), c3p = fastcos(phi[3]);
        z[(size_t)row0 * 4 + 0] = fastcos(oA0.x) * c0p;
        z[(size_t)row0 * 4 + 1] = fastcos(oA0.y) * c1p;
        z[(size_t)row0 * 4 + 2] = fastcos(oA0.z) * c2p;
        z[(size_t)row0 * 4 + 3] = fastcos(oA0.w) * c3p;
        z[(size_t)(row0 + 1) * 4 + 0] = fastcos(oB0.x) * c0p;
        z[(size_t)(row0 + 1) * 4 + 1] = fastcos(oB0.y) * c1p;
        z[(size_t)(row0 + 1) * 4 + 2] = fastcos(oB0.z) * c2p;
        z[(size_t)(row0 + 1) * 4 + 3] = fastcos(oB0.w) * c3p;
    }
    if (acos != nullptr) {
        f32x4 t0 = *(const f32x4*)(theta + lane * 4);
        f32x4 t1 = *(const f32x4*)(theta + 256 + lane * 4);
        ushort4 cA0, cA1, cB0, cB1;
        cA0.x = f2bf(fastcos(oA0.x + t0.x));
        cA0.y = f2bf(fastcos(oA0.y + t0.y));
        cA0.z = f2bf(fastcos(oA0.z + t0.z));
        cA0.w = f2bf(fastcos(oA0.w + t0.w));
        cA1.x = f2bf(fastcos(oA1.x + t1.x));
        cA1.y = f2bf(fastcos(oA1.y + t1.y));
        cA1.z = f2bf(fastcos(oA1.z + t1.z));
        cA1.w = f2bf(fastcos(oA1.w + t1.w));
        cB0.x = f2bf(fastcos(oB0.x + t0.x));
        cB0.y = f2bf(fastcos(oB0.y + t0.y));
        cB0.z = f2bf(fastcos(oB0.z + t0.z));
        cB0.w = f2bf(fastcos(oB0.w + t0.w));
        cB1.x = f2bf(fastcos(oB1.x + t1.x));
        cB1.y = f2bf(fastcos(oB1.y + t1.y));
        cB1.z = f2bf(fastcos(oB1.z + t1.z));
        cB1.w = f2bf(fastcos(oB1.w + t1.w));
        *(ushort4*)(acos + (size_t)row0 * Ee + lane * 4) = cA0;
        *(ushort4*)(acos + (size_t)row0 * Ee + 256 + lane * 4) = cA1;
        *(ushort4*)(acos + (size_t)(row0 + 1) * Ee + lane * 4) = cB0;
        *(ushort4*)(acos + (size_t)(row0 + 1) * Ee + 256 + lane * 4) = cB1;
    }
}

// ---------------- parallel pool: partial sums over 64-row chunks --------
__global__ __launch_bounds__(256) void pool_part(const float* __restrict__ x,
                                                 float* __restrict__ part) {
    int bidx = blockIdx.x, ch = blockIdx.y;
    int t = threadIdx.x;
    float s0 = 0.f, s1 = 0.f;
    for (int s = 0; s < 64; ++s) {
        const float* row = x + ((size_t)bidx * Ss + ch * 64 + s) * Ee;
        s0 += row[t];
        s1 += row[t + 256];
    }
    float* pr = part + ((size_t)(bidx * 32 + ch)) * Ee;
    pr[t] = s0;
    pr[t + 256] = s1;
}

// ---------------- finish pool + classifier ----------------
__global__ __launch_bounds__(256) void cls_kernel(const float* __restrict__ part,
                                                  const float* __restrict__ clsW,
                                                  const float* __restrict__ clsb,
                                                  float* __restrict__ out) {
    int bidx = blockIdx.x;
    int t = threadIdx.x;
    float p0 = 0.f, p1 = 0.f;
    for (int ch = 0; ch < 32; ++ch) {
        const float* pr = part + ((size_t)(bidx * 32 + ch)) * Ee;
        p0 += pr[t];
        p1 += pr[t + 256];
    }
    p0 *= (1.f / float(Ss));
    p1 *= (1.f / float(Ss));
    __shared__ float red[256];
    for (int c = 0; c < Cc; ++c) {
        red[t] = p0 * clsW[(size_t)c * Ee + t] + p1 * clsW[(size_t)c * Ee + t + 256];
        __syncthreads();
        for (int s2 = 128; s2 > 0; s2 >>= 1) {
            if (t < s2) red[t] += red[t + s2];
            __syncthreads();
        }
        if (t == 0) out[bidx * Cc + c] = red[0] + clsb[c];
        __syncthreads();
    }
}

extern "C" void kernel_launch(void* const* d_in, const int* in_sizes, int n_in,
                              void* d_out, int out_size, void* d_ws, size_t ws_size,
                              hipStream_t stream) {
    const int*   tokens     = (const int*)d_in[0];
    const float* emb        = (const float*)d_in[1];
    const float* theta_attn = (const float*)d_in[2];
    const float* combine_W  = (const float*)d_in[3];
    const float* combine_b  = (const float*)d_in[4];
    const float* ln1_g      = (const float*)d_in[5];
    const float* ln1_b      = (const float*)d_in[6];
    const float* phi_ffn    = (const float*)d_in[7];
    const float* lin1_W     = (const float*)d_in[8];
    const float* lin1_b     = (const float*)d_in[9];
    const float* lin2_W     = (const float*)d_in[10];
    const float* lin2_b     = (const float*)d_in[11];
    const float* ln2_g      = (const float*)d_in[12];
    const float* ln2_b      = (const float*)d_in[13];
    const float* cls_W      = (const float*)d_in[14];
    const float* cls_b      = (const float*)d_in[15];
    float* out = (float*)d_out;

    float* x    = (float*)d_ws;                             // 32MB fp32
    unsigned short* tmpb = (unsigned short*)(x + (size_t)Nn * Ee);  // 16MB bf16
    float* z    = (float*)(tmpb + (size_t)Nn * Ee);         // 256KB
    float* part = z + (size_t)Nn * 4;                       // 512KB
    unsigned short* Wcb  = (unsigned short*)(part + (size_t)Bb * 32 * Ee); // 3MB
    unsigned short* W2b  = Wcb + (size_t)Ll * Ee * Ee;                     // 12MB
    unsigned short* acos = W2b + (size_t)Ll * Ee * Ff;                     // 16MB
    unsigned short* H    = acos + (size_t)Nn * Ee;                         // 64MB
    float* pe = (float*)H;  // overlay: pe (4MB) only used before first h_kernel

    {
        int total = Ss * (Ee / 2);
        pe_kernel<<<(total + 255) / 256, 256, 0, stream>>>(pe);
    }
    {
        int total = Nn * Ee / 4;
        embed_kernel<<<(total + 255) / 256, 256, 0, stream>>>(
            tokens, emb, pe, theta_attn, x, acos);
    }
    {
        int n4c = Ll * Ee * Ee / 4;
        cvt_bf16<<<(n4c + 255) / 256, 256, 0, stream>>>(combine_W, Wcb, n4c);
        int n42 = Ll * Ee * Ff / 4;
        cvt_bf16<<<(n42 + 255) / 256, 256, 0, stream>>>(lin2_W, W2b, n42);
    }

    const int ngemm = (Nn / 128) * (Ee / 128);  // 512 blocks, 1D + swizzle
    for (int l = 0; l < Ll; l++) {
        const unsigned short* cWl = Wcb + (size_t)l * Ee * Ee;
        const float* cbl  = combine_b + (size_t)l * Ee;
        const float* g1   = ln1_g + (size_t)l * Ee;
        const float* b1n  = ln1_b + (size_t)l * Ee;
        const float* phil = phi_ffn + (size_t)l * 4;
        const float* w1l  = lin1_W + (size_t)l * Ff * 4;
        const float* b1l  = lin1_b + (size_t)l * Ff;
        const unsigned short* w2l = W2b + (size_t)l * Ee * Ff;
        const float* b2l  = lin2_b + (size_t)l * Ee;
        const float* g2   = ln2_g + (size_t)l * Ee;
        const float* b2n  = ln2_b + (size_t)l * Ee;
        const float* thn  = (l + 1 < Ll) ? theta_attn + (size_t)(l + 1) * Ee : nullptr;
        unsigned short* acn = (l + 1 < Ll) ? acos : nullptr;

        // tmpb = bf16(x + Acos @ Wc^T + cb)
        gemm_bf16<<<ngemm, 512, 0, stream>>>(acos, cWl, cbl, x, tmpb, Ee);
        // x = LN(tmpb); z = cos(x[:,:4])*cos(phi)
        ln_fused<<<Nn / 8, 256, 0, stream>>>(tmpb, x, g1, b1n, phil, z,
                                             nullptr, nullptr);
        // H = bf16(relu(z @ W1^T + b1))
        h_kernel<<<Nn / 8, 256, 0, stream>>>(z, w1l, b1l, H);
        // tmpb = bf16(x + H @ W2^T + b2)
        gemm_bf16<<<ngemm, 512, 0, stream>>>(H, w2l, b2l, x, tmpb, Ff);
        // x = LN(tmpb); Acos = bf16(cos(x + theta_{l+1}))  (except last layer)
        ln_fused<<<Nn / 8, 256, 0, stream>>>(tmpb, x, g2, b2n, nullptr, nullptr,
                                             thn, acn);
    }

    pool_part<<<dim3(Bb, 32), 256, 0, stream>>>(x, part);
    cls_kernel<<<Bb, 256, 0, stream>>>(part, cls_W, cls_b, out);
}

// Round 15
// 613.154 us; speedup vs baseline: 1.0762x; 1.0762x over previous
//
#include <hip/hip_runtime.h>
#include <hip/hip_bf16.h>
#include <math.h>

#define LN_EPS 1e-5f

constexpr int Bb = 8, Ss = 2048, Ee = 512, Ll = 6, Ff = 2048, Cc = 10;
constexpr int Nn = Bb * Ss;  // 16384 rows

typedef __attribute__((ext_vector_type(8))) short short8v;
typedef __attribute__((ext_vector_type(4))) float f32x4;

__device__ __forceinline__ unsigned short f2bf(float f) {
    unsigned int b = __float_as_uint(f);
    b += 0x7FFFu + ((b >> 16) & 1u);   // RNE
    return (unsigned short)(b >> 16);
}

__device__ __forceinline__ float bf2f(unsigned short u) {
    return __uint_as_float((unsigned int)u << 16);
}

__device__ __forceinline__ float fastcos(float x) {
    float r = x * 0.15915494309189535f;     // radians -> revolutions
    r = __builtin_amdgcn_fractf(r);         // reduce to [0,1)
    return __builtin_amdgcn_cosf(r);        // v_cos_f32
}

// async global->LDS, 16B per lane. LDS dest = wave-uniform base + lane*16.
__device__ __forceinline__ void gload16(const void* g, void* lds) {
    __builtin_amdgcn_global_load_lds(
        (__attribute__((address_space(1))) void*)(g),
        (__attribute__((address_space(3))) void*)(lds),
        16, 0, 0);
}

// ---------------- positional encoding table ----------------
__global__ void pe_kernel(float* __restrict__ pe) {
    int p = blockIdx.x * blockDim.x + threadIdx.x;
    int total = Ss * (Ee / 2);
    if (p >= total) return;
    int s = p / (Ee / 2);
    int i = p % (Ee / 2);
    float div = expf(float(2 * i) * (-logf(10000.0f) / float(Ee)));
    float ang = float(s) * div;
    pe[s * Ee + 2 * i]     = sinf(ang);
    pe[s * Ee + 2 * i + 1] = cosf(ang);
}

// ------- embedding + PE -> x (bf16) + Acos for layer 0 -------
__global__ void embed_kernel(const int* __restrict__ tokens,
                             const float* __restrict__ emb,
                             const float* __restrict__ pe,
                             const float* __restrict__ theta0,
                             unsigned short* __restrict__ x,
                             unsigned short* __restrict__ acos) {
    int idx = blockIdx.x * blockDim.x + threadIdx.x;
    int total = Nn * Ee / 4;
    if (idx >= total) return;
    int n  = idx / (Ee / 4);
    int e4 = idx % (Ee / 4);
    int tok = tokens[n];
    int s = n % Ss;
    f32x4 a = *(const f32x4*)(emb + (size_t)tok * Ee + e4 * 4);
    f32x4 p = *(const f32x4*)(pe + (size_t)s * Ee + e4 * 4);
    f32x4 o = a + p;
    ushort4 xo;
    xo.x = f2bf(o.x); xo.y = f2bf(o.y); xo.z = f2bf(o.z); xo.w = f2bf(o.w);
    *(ushort4*)(x + (size_t)n * Ee + e4 * 4) = xo;
    f32x4 t = *(const f32x4*)(theta0 + e4 * 4);
    ushort4 c;
    c.x = f2bf(fastcos(o.x + t.x));
    c.y = f2bf(fastcos(o.y + t.y));
    c.z = f2bf(fastcos(o.z + t.z));
    c.w = f2bf(fastcos(o.w + t.w));
    *(ushort4*)(acos + (size_t)n * Ee + e4 * 4) = c;
}

// ---------------- fp32 -> bf16 weight conversion ----------------
__global__ void cvt_bf16(const float* __restrict__ in,
                         unsigned short* __restrict__ out, int n4) {
    int i = blockIdx.x * blockDim.x + threadIdx.x;
    if (i >= n4) return;
    f32x4 v = *(const f32x4*)(in + (size_t)i * 4);
    ushort4 o;
    o.x = f2bf(v.x); o.y = f2bf(v.y); o.z = f2bf(v.z); o.w = f2bf(v.w);
    *(ushort4*)(out + (size_t)i * 4) = o;
}

// ---------------- H = bf16(relu(z @ W1^T + b1)) ----------------
__global__ __launch_bounds__(256) void h_kernel(const float* __restrict__ z,
                                                const float* __restrict__ W1,
                                                const float* __restrict__ b1,
                                                unsigned short* __restrict__ H) {
    __shared__ unsigned short hls[8 * Ff];
    const int t  = threadIdx.x;
    const int m0 = blockIdx.x * 8;
    f32x4 zr[8];
#pragma unroll
    for (int r = 0; r < 8; ++r)
        zr[r] = *(const f32x4*)(z + (size_t)(m0 + r) * 4);
#pragma unroll
    for (int j = 0; j < 8; ++j) {
        const int f = t + 256 * j;
        f32x4 w = *(const f32x4*)(W1 + (size_t)f * 4);  // coalesced
        float bb = b1[f];                               // coalesced
#pragma unroll
        for (int r = 0; r < 8; ++r) {
            float v = zr[r].x * w.x + zr[r].y * w.y + zr[r].z * w.z +
                      zr[r].w * w.w + bb;
            hls[r * Ff + f] = f2bf(fmaxf(v, 0.f));
        }
    }
    __syncthreads();
#pragma unroll
    for (int j = 0; j < 8; ++j) {
        const int idx = (j * 256 + t) * 8;   // ushort index, 16B per thread
        *(short8v*)(H + (size_t)m0 * Ff + idx) = *(const short8v*)(&hls[idx]);
    }
}

// ==== bf16 GEMM: Coutb = bf16(A @ Wb^T + bias + xres), xres bf16 ====
// Round-13 structure (best): 128x128 tile, BK=64, 8 waves, depth-2
// prefetch over 2 LDS buffers via reg-hoisted fragments.
__global__ __launch_bounds__(512, 4) void gemm_bf16(
    const unsigned short* __restrict__ A,
    const unsigned short* __restrict__ Wb,
    const float* __restrict__ bias,
    const unsigned short* __restrict__ xres,
    unsigned short* __restrict__ Coutb,
    int K) {
    __shared__ unsigned short As[2][128 * 64];
    __shared__ unsigned short Bs[2][128 * 64];
    const int tid  = threadIdx.x;
    const int lane = tid & 63;
    const int wid  = tid >> 6;     // 0..7
    const int wr   = wid >> 2;     // 0..1 (64-row band)
    const int wc   = wid & 3;      // 0..3 (32-col band)
    const int wg   = blockIdx.x;
    const int sw   = (wg & 7) * 64 + (wg >> 3);
    const int row0 = (sw >> 2) * 128;
    const int col0 = (sw & 3) * 128;
    const int srow   = lane >> 3;
    const int pchunk = lane & 7;

    f32x4 acc[4][2];
#pragma unroll
    for (int m = 0; m < 4; m++)
#pragma unroll
        for (int n = 0; n < 2; n++) acc[m][n] = {0.f, 0.f, 0.f, 0.f};

    const int NT = K >> 6;

    auto STAGE = [&](int buf, int k0) {
#pragma unroll
        for (int i = 0; i < 2; ++i) {
            const int s   = wid * 2 + i;
            const int row = s * 8 + srow;
            const int lc  = pchunk ^ (row & 7);
            gload16(A  + (size_t)(row0 + row) * K + k0 + lc * 8, &As[buf][s * 512]);
        }
#pragma unroll
        for (int i = 0; i < 2; ++i) {
            const int s   = wid * 2 + i;
            const int row = s * 8 + srow;
            const int lc  = pchunk ^ (row & 7);
            gload16(Wb + (size_t)(col0 + row) * K + k0 + lc * 8, &Bs[buf][s * 512]);
        }
    };

    STAGE(0, 0);
    if (NT > 1) STAGE(1, 64);
    for (int kt = 0; kt < NT; ++kt) {
        const int b = kt & 1;
        if (kt + 1 < NT) {
            asm volatile("s_waitcnt vmcnt(4)" ::: "memory");
        } else {
            asm volatile("s_waitcnt vmcnt(0)" ::: "memory");
        }
        __builtin_amdgcn_s_barrier();
        asm volatile("" ::: "memory");
        short8v aF[2][4], bF[2][2];
#pragma unroll
        for (int ks = 0; ks < 2; ks++) {
            const int k8 = ks * 4 + (lane >> 4);
#pragma unroll
            for (int m = 0; m < 4; m++) {
                const int row = wr * 64 + m * 16 + (lane & 15);
                aF[ks][m] = *(const short8v*)(&As[b][row * 64 + ((k8 ^ (row & 7)) * 8)]);
            }
#pragma unroll
            for (int n = 0; n < 2; n++) {
                const int row = wc * 32 + n * 16 + (lane & 15);
                bF[ks][n] = *(const short8v*)(&Bs[b][row * 64 + ((k8 ^ (row & 7)) * 8)]);
            }
        }
        asm volatile("s_waitcnt lgkmcnt(0)" ::: "memory");
        __builtin_amdgcn_s_barrier();
        asm volatile("" ::: "memory");
        if (kt + 2 < NT) STAGE(b, (kt + 2) << 6);
#pragma unroll
        for (int ks = 0; ks < 2; ks++)
#pragma unroll
            for (int m = 0; m < 4; m++)
#pragma unroll
                for (int n = 0; n < 2; n++)
                    acc[m][n] = __builtin_amdgcn_mfma_f32_16x16x32_bf16(
                        aF[ks][m], bF[ks][n], acc[m][n], 0, 0, 0);
    }

#pragma unroll
    for (int m = 0; m < 4; m++) {
#pragma unroll
        for (int n = 0; n < 2; n++) {
            int colg = col0 + wc * 32 + n * 16 + (lane & 15);
            float bv = bias[colg];
#pragma unroll
            for (int j = 0; j < 4; j++) {
                int rowg = row0 + wr * 64 + m * 16 + ((lane >> 4) * 4) + j;
                size_t off = (size_t)rowg * 512 + colg;
                Coutb[off] = f2bf(acc[m][n][j] + bv + bf2f(xres[off]));
            }
        }
    }
}

// -- LN: 2 rows per wave on bf16 tmp -> bf16 x; optional z/Acos fusion --
__global__ __launch_bounds__(256) void ln_fused(
    const unsigned short* __restrict__ tmp, unsigned short* __restrict__ x,
    const float* __restrict__ g, const float* __restrict__ b,
    const float* __restrict__ phi, float* __restrict__ z,
    const float* __restrict__ theta, unsigned short* __restrict__ acos) {
    const int wv   = threadIdx.x >> 6;
    const int lane = threadIdx.x & 63;
    const int row0 = blockIdx.x * 8 + wv * 2;  // this wave: row0, row0+1

    f32x4 g0 = *(const f32x4*)(g + lane * 4);
    f32x4 b0 = *(const f32x4*)(b + lane * 4);
    f32x4 g1 = *(const f32x4*)(g + 256 + lane * 4);
    f32x4 b1v = *(const f32x4*)(b + 256 + lane * 4);

    f32x4 vA0, vA1, vB0, vB1;
    {
        const unsigned short* t0 = tmp + (size_t)row0 * Ee;
        const unsigned short* t1 = tmp + (size_t)(row0 + 1) * Ee;
        ushort4 a0 = *(const ushort4*)(t0 + lane * 4);
        ushort4 a1 = *(const ushort4*)(t0 + 256 + lane * 4);
        ushort4 c0 = *(const ushort4*)(t1 + lane * 4);
        ushort4 c1 = *(const ushort4*)(t1 + 256 + lane * 4);
        vA0 = {bf2f(a0.x), bf2f(a0.y), bf2f(a0.z), bf2f(a0.w)};
        vA1 = {bf2f(a1.x), bf2f(a1.y), bf2f(a1.z), bf2f(a1.w)};
        vB0 = {bf2f(c0.x), bf2f(c0.y), bf2f(c0.z), bf2f(c0.w)};
        vB1 = {bf2f(c1.x), bf2f(c1.y), bf2f(c1.z), bf2f(c1.w)};
    }
    float s0 = vA0.x + vA0.y + vA0.z + vA0.w + vA1.x + vA1.y + vA1.z + vA1.w;
    float s1 = vB0.x + vB0.y + vB0.z + vB0.w + vB1.x + vB1.y + vB1.z + vB1.w;
#pragma unroll
    for (int o = 32; o; o >>= 1) {
        s0 += __shfl_xor(s0, o);
        s1 += __shfl_xor(s1, o);
    }
    float mu0 = s0 * (1.f / 512.f), mu1 = s1 * (1.f / 512.f);
    f32x4 dA0 = {vA0.x - mu0, vA0.y - mu0, vA0.z - mu0, vA0.w - mu0};
    f32x4 dA1 = {vA1.x - mu0, vA1.y - mu0, vA1.z - mu0, vA1.w - mu0};
    f32x4 dB0 = {vB0.x - mu1, vB0.y - mu1, vB0.z - mu1, vB0.w - mu1};
    f32x4 dB1 = {vB1.x - mu1, vB1.y - mu1, vB1.z - mu1, vB1.w - mu1};
    float q0 = dA0.x * dA0.x + dA0.y * dA0.y + dA0.z * dA0.z + dA0.w * dA0.w +
               dA1.x * dA1.x + dA1.y * dA1.y + dA1.z * dA1.z + dA1.w * dA1.w;
    float q1 = dB0.x * dB0.x + dB0.y * dB0.y + dB0.z * dB0.z + dB0.w * dB0.w +
               dB1.x * dB1.x + dB1.y * dB1.y + dB1.z * dB1.z + dB1.w * dB1.w;
#pragma unroll
    for (int o = 32; o; o >>= 1) {
        q0 += __shfl_xor(q0, o);
        q1 += __shfl_xor(q1, o);
    }
    float rs0 = rsqrtf(q0 * (1.f / 512.f) + LN_EPS);
    float rs1 = rsqrtf(q1 * (1.f / 512.f) + LN_EPS);

    f32x4 oA0 = {dA0.x * rs0 * g0.x + b0.x, dA0.y * rs0 * g0.y + b0.y,
                 dA0.z * rs0 * g0.z + b0.z, dA0.w * rs0 * g0.w + b0.w};
    f32x4 oA1 = {dA1.x * rs0 * g1.x + b1v.x, dA1.y * rs0 * g1.y + b1v.y,
                 dA1.z * rs0 * g1.z + b1v.z, dA1.w * rs0 * g1.w + b1v.w};
    f32x4 oB0 = {dB0.x * rs1 * g0.x + b0.x, dB0.y * rs1 * g0.y + b0.y,
                 dB0.z * rs1 * g0.z + b0.z, dB0.w * rs1 * g0.w + b0.w};
    f32x4 oB1 = {dB1.x * rs1 * g1.x + b1v.x, dB1.y * rs1 * g1.y + b1v.y,
                 dB1.z * rs1 * g1.z + b1v.z, dB1.w * rs1 * g1.w + b1v.w};
    ushort4 xA0 = {f2bf(oA0.x), f2bf(oA0.y), f2bf(oA0.z), f2bf(oA0.w)};
    ushort4 xA1 = {f2bf(oA1.x), f2bf(oA1.y), f2bf(oA1.z), f2bf(oA1.w)};
    ushort4 xB0 = {f2bf(oB0.x), f2bf(oB0.y), f2bf(oB0.z), f2bf(oB0.w)};
    ushort4 xB1 = {f2bf(oB1.x), f2bf(oB1.y), f2bf(oB1.z), f2bf(oB1.w)};
    *(ushort4*)(x + (size_t)row0 * Ee + lane * 4) = xA0;
    *(ushort4*)(x + (size_t)row0 * Ee + 256 + lane * 4) = xA1;
    *(ushort4*)(x + (size_t)(row0 + 1) * Ee + lane * 4) = xB0;
    *(ushort4*)(x + (size_t)(row0 + 1) * Ee + 256 + lane * 4) = xB1;
    if (z != nullptr && lane == 0) {
        float c0p = fastcos(phi[0]), c1p = fastcos(phi[1]);
        float c2p = fastcos(phi[2]), c3p = fastcos(phi[3]);
        z[(size_t)row0 * 4 + 0] = fastcos(oA0.x) * c0p;
        z[(size_t)row0 * 4 + 1] = fastcos(oA0.y) * c1p;
        z[(size_t)row0 * 4 + 2] = fastcos(oA0.z) * c2p;
        z[(size_t)row0 * 4 + 3] = fastcos(oA0.w) * c3p;
        z[(size_t)(row0 + 1) * 4 + 0] = fastcos(oB0.x) * c0p;
        z[(size_t)(row0 + 1) * 4 + 1] = fastcos(oB0.y) * c1p;
        z[(size_t)(row0 + 1) * 4 + 2] = fastcos(oB0.z) * c2p;
        z[(size_t)(row0 + 1) * 4 + 3] = fastcos(oB0.w) * c3p;
    }
    if (acos != nullptr) {
        f32x4 t0 = *(const f32x4*)(theta + lane * 4);
        f32x4 t1 = *(const f32x4*)(theta + 256 + lane * 4);
        ushort4 cA0, cA1, cB0, cB1;
        cA0.x = f2bf(fastcos(oA0.x + t0.x));
        cA0.y = f2bf(fastcos(oA0.y + t0.y));
        cA0.z = f2bf(fastcos(oA0.z + t0.z));
        cA0.w = f2bf(fastcos(oA0.w + t0.w));
        cA1.x = f2bf(fastcos(oA1.x + t1.x));
        cA1.y = f2bf(fastcos(oA1.y + t1.y));
        cA1.z = f2bf(fastcos(oA1.z + t1.z));
        cA1.w = f2bf(fastcos(oA1.w + t1.w));
        cB0.x = f2bf(fastcos(oB0.x + t0.x));
        cB0.y = f2bf(fastcos(oB0.y + t0.y));
        cB0.z = f2bf(fastcos(oB0.z + t0.z));
        cB0.w = f2bf(fastcos(oB0.w + t0.w));
        cB1.x = f2bf(fastcos(oB1.x + t1.x));
        cB1.y = f2bf(fastcos(oB1.y + t1.y));
        cB1.z = f2bf(fastcos(oB1.z + t1.z));
        cB1.w = f2bf(fastcos(oB1.w + t1.w));
        *(ushort4*)(acos + (size_t)row0 * Ee + lane * 4) = cA0;
        *(ushort4*)(acos + (size_t)row0 * Ee + 256 + lane * 4) = cA1;
        *(ushort4*)(acos + (size_t)(row0 + 1) * Ee + lane * 4) = cB0;
        *(ushort4*)(acos + (size_t)(row0 + 1) * Ee + 256 + lane * 4) = cB1;
    }
}

// ------- parallel pool (bf16 x): partial sums over 64-row chunks -------
__global__ __launch_bounds__(256) void pool_part(const unsigned short* __restrict__ x,
                                                 float* __restrict__ part) {
    int bidx = blockIdx.x, ch = blockIdx.y;
    int t = threadIdx.x;
    float s0 = 0.f, s1 = 0.f;
    for (int s = 0; s < 64; ++s) {
        const unsigned short* row = x + ((size_t)bidx * Ss + ch * 64 + s) * Ee;
        s0 += bf2f(row[t]);
        s1 += bf2f(row[t + 256]);
    }
    float* pr = part + ((size_t)(bidx * 32 + ch)) * Ee;
    pr[t] = s0;
    pr[t + 256] = s1;
}

// ---------------- finish pool + classifier ----------------
__global__ __launch_bounds__(256) void cls_kernel(const float* __restrict__ part,
                                                  const float* __restrict__ clsW,
                                                  const float* __restrict__ clsb,
                                                  float* __restrict__ out) {
    int bidx = blockIdx.x;
    int t = threadIdx.x;
    float p0 = 0.f, p1 = 0.f;
    for (int ch = 0; ch < 32; ++ch) {
        const float* pr = part + ((size_t)(bidx * 32 + ch)) * Ee;
        p0 += pr[t];
        p1 += pr[t + 256];
    }
    p0 *= (1.f / float(Ss));
    p1 *= (1.f / float(Ss));
    __shared__ float red[256];
    for (int c = 0; c < Cc; ++c) {
        red[t] = p0 * clsW[(size_t)c * Ee + t] + p1 * clsW[(size_t)c * Ee + t + 256];
        __syncthreads();
        for (int s2 = 128; s2 > 0; s2 >>= 1) {
            if (t < s2) red[t] += red[t + s2];
            __syncthreads();
        }
        if (t == 0) out[bidx * Cc + c] = red[0] + clsb[c];
        __syncthreads();
    }
}

extern "C" void kernel_launch(void* const* d_in, const int* in_sizes, int n_in,
                              void* d_out, int out_size, void* d_ws, size_t ws_size,
                              hipStream_t stream) {
    const int*   tokens     = (const int*)d_in[0];
    const float* emb        = (const float*)d_in[1];
    const float* theta_attn = (const float*)d_in[2];
    const float* combine_W  = (const float*)d_in[3];
    const float* combine_b  = (const float*)d_in[4];
    const float* ln1_g      = (const float*)d_in[5];
    const float* ln1_b      = (const float*)d_in[6];
    const float* phi_ffn    = (const float*)d_in[7];
    const float* lin1_W     = (const float*)d_in[8];
    const float* lin1_b     = (const float*)d_in[9];
    const float* lin2_W     = (const float*)d_in[10];
    const float* lin2_b     = (const float*)d_in[11];
    const float* ln2_g      = (const float*)d_in[12];
    const float* ln2_b      = (const float*)d_in[13];
    const float* cls_W      = (const float*)d_in[14];
    const float* cls_b      = (const float*)d_in[15];
    float* out = (float*)d_out;

    unsigned short* x    = (unsigned short*)d_ws;            // 16MB bf16
    unsigned short* tmpb = x + (size_t)Nn * Ee;              // 16MB bf16
    float* z    = (float*)(tmpb + (size_t)Nn * Ee);          // 256KB
    float* part = z + (size_t)Nn * 4;                        // 512KB
    unsigned short* Wcb  = (unsigned short*)(part + (size_t)Bb * 32 * Ee); // 3MB
    unsigned short* W2b  = Wcb + (size_t)Ll * Ee * Ee;                     // 12MB
    unsigned short* acos = W2b + (size_t)Ll * Ee * Ff;                     // 16MB
    unsigned short* H    = acos + (size_t)Nn * Ee;                         // 64MB
    float* pe = (float*)H;  // overlay: pe (4MB) only used before first h_kernel

    {
        int total = Ss * (Ee / 2);
        pe_kernel<<<(total + 255) / 256, 256, 0, stream>>>(pe);
    }
    {
        int total = Nn * Ee / 4;
        embed_kernel<<<(total + 255) / 256, 256, 0, stream>>>(
            tokens, emb, pe, theta_attn, x, acos);
    }
    {
        int n4c = Ll * Ee * Ee / 4;
        cvt_bf16<<<(n4c + 255) / 256, 256, 0, stream>>>(combine_W, Wcb, n4c);
        int n42 = Ll * Ee * Ff / 4;
        cvt_bf16<<<(n42 + 255) / 256, 256, 0, stream>>>(lin2_W, W2b, n42);
    }

    const int ngemm = (Nn / 128) * (Ee / 128);  // 512 blocks, 1D + swizzle
    for (int l = 0; l < Ll; l++) {
        const unsigned short* cWl = Wcb + (size_t)l * Ee * Ee;
        const float* cbl  = combine_b + (size_t)l * Ee;
        const float* g1   = ln1_g + (size_t)l * Ee;
        const float* b1n  = ln1_b + (size_t)l * Ee;
        const float* phil = phi_ffn + (size_t)l * 4;
        const float* w1l  = lin1_W + (size_t)l * Ff * 4;
        const float* b1l  = lin1_b + (size_t)l * Ff;
        const unsigned short* w2l = W2b + (size_t)l * Ee * Ff;
        const float* b2l  = lin2_b + (size_t)l * Ee;
        const float* g2   = ln2_g + (size_t)l * Ee;
        const float* b2n  = ln2_b + (size_t)l * Ee;
        const float* thn  = (l + 1 < Ll) ? theta_attn + (size_t)(l + 1) * Ee : nullptr;
        unsigned short* acn = (l + 1 < Ll) ? acos : nullptr;

        // tmpb = bf16(x + Acos @ Wc^T + cb)
        gemm_bf16<<<ngemm, 512, 0, stream>>>(acos, cWl, cbl, x, tmpb, Ee);
        // x = bf16(LN(tmpb)); z = cos(LN[:,:4])*cos(phi)
        ln_fused<<<Nn / 8, 256, 0, stream>>>(tmpb, x, g1, b1n, phil, z,
                                             nullptr, nullptr);
        // H = bf16(relu(z @ W1^T + b1))
        h_kernel<<<Nn / 8, 256, 0, stream>>>(z, w1l, b1l, H);
        // tmpb = bf16(x + H @ W2^T + b2)
        gemm_bf16<<<ngemm, 512, 0, stream>>>(H, w2l, b2l, x, tmpb, Ff);
        // x = bf16(LN(tmpb)); Acos = bf16(cos(LN + theta_{l+1}))
        ln_fused<<<Nn / 8, 256, 0, stream>>>(tmpb, x, g2, b2n, nullptr, nullptr,
                                             thn, acn);
    }

    pool_part<<<dim3(Bb, 32), 256, 0, stream>>>(x, part);
    cls_kernel<<<Bb, 256, 0, stream>>>(part, cls_W, cls_b, out);
}

// Round 16
// 592.443 us; speedup vs baseline: 1.1138x; 1.0350x over previous
//
#include <hip/hip_runtime.h>
#include <hip/hip_bf16.h>
#include <math.h>

#define LN_EPS 1e-5f

constexpr int Bb = 8, Ss = 2048, Ee = 512, Ll = 6, Ff = 2048, Cc = 10;
constexpr int Nn = Bb * Ss;  // 16384 rows

typedef __attribute__((ext_vector_type(8))) short short8v;
typedef __attribute__((ext_vector_type(4))) float f32x4;

__device__ __forceinline__ unsigned short f2bf(float f) {
    unsigned int b = __float_as_uint(f);
    b += 0x7FFFu + ((b >> 16) & 1u);   // RNE
    return (unsigned short)(b >> 16);
}

__device__ __forceinline__ float bf2f(unsigned short u) {
    return __uint_as_float((unsigned int)u << 16);
}

__device__ __forceinline__ float fastcos(float x) {
    float r = x * 0.15915494309189535f;     // radians -> revolutions
    r = __builtin_amdgcn_fractf(r);         // reduce to [0,1)
    return __builtin_amdgcn_cosf(r);        // v_cos_f32
}

// async global->LDS, 16B per lane. LDS dest = wave-uniform base + lane*16.
__device__ __forceinline__ void gload16(const void* g, void* lds) {
    __builtin_amdgcn_global_load_lds(
        (__attribute__((address_space(1))) void*)(g),
        (__attribute__((address_space(3))) void*)(lds),
        16, 0, 0);
}

// ---------------- positional encoding table ----------------
__global__ void pe_kernel(float* __restrict__ pe) {
    int p = blockIdx.x * blockDim.x + threadIdx.x;
    int total = Ss * (Ee / 2);
    if (p >= total) return;
    int s = p / (Ee / 2);
    int i = p % (Ee / 2);
    float div = expf(float(2 * i) * (-logf(10000.0f) / float(Ee)));
    float ang = float(s) * div;
    pe[s * Ee + 2 * i]     = sinf(ang);
    pe[s * Ee + 2 * i + 1] = cosf(ang);
}

// ------- embedding + PE -> x (bf16) + Acos for layer 0 -------
__global__ void embed_kernel(const int* __restrict__ tokens,
                             const float* __restrict__ emb,
                             const float* __restrict__ pe,
                             const float* __restrict__ theta0,
                             unsigned short* __restrict__ x,
                             unsigned short* __restrict__ acos) {
    int idx = blockIdx.x * blockDim.x + threadIdx.x;
    int total = Nn * Ee / 4;
    if (idx >= total) return;
    int n  = idx / (Ee / 4);
    int e4 = idx % (Ee / 4);
    int tok = tokens[n];
    int s = n % Ss;
    f32x4 a = *(const f32x4*)(emb + (size_t)tok * Ee + e4 * 4);
    f32x4 p = *(const f32x4*)(pe + (size_t)s * Ee + e4 * 4);
    f32x4 o = a + p;
    ushort4 xo;
    xo.x = f2bf(o.x); xo.y = f2bf(o.y); xo.z = f2bf(o.z); xo.w = f2bf(o.w);
    *(ushort4*)(x + (size_t)n * Ee + e4 * 4) = xo;
    f32x4 t = *(const f32x4*)(theta0 + e4 * 4);
    ushort4 c;
    c.x = f2bf(fastcos(o.x + t.x));
    c.y = f2bf(fastcos(o.y + t.y));
    c.z = f2bf(fastcos(o.z + t.z));
    c.w = f2bf(fastcos(o.w + t.w));
    *(ushort4*)(acos + (size_t)n * Ee + e4 * 4) = c;
}

// ---------------- fp32 -> bf16 weight conversion ----------------
__global__ void cvt_bf16(const float* __restrict__ in,
                         unsigned short* __restrict__ out, int n4) {
    int i = blockIdx.x * blockDim.x + threadIdx.x;
    if (i >= n4) return;
    f32x4 v = *(const f32x4*)(in + (size_t)i * 4);
    ushort4 o;
    o.x = f2bf(v.x); o.y = f2bf(v.y); o.z = f2bf(v.z); o.w = f2bf(v.w);
    *(ushort4*)(out + (size_t)i * 4) = o;
}

// ==== bf16 GEMM: Coutb = bf16(A @ Wb^T + bias + xres), xres bf16 ====
// Round-13 structure (best): 128x128 tile, BK=64, 8 waves, depth-2
// prefetch over 2 LDS buffers via reg-hoisted fragments.
__global__ __launch_bounds__(512, 4) void gemm_bf16(
    const unsigned short* __restrict__ A,
    const unsigned short* __restrict__ Wb,
    const float* __restrict__ bias,
    const unsigned short* __restrict__ xres,
    unsigned short* __restrict__ Coutb,
    int K) {
    __shared__ unsigned short As[2][128 * 64];
    __shared__ unsigned short Bs[2][128 * 64];
    const int tid  = threadIdx.x;
    const int lane = tid & 63;
    const int wid  = tid >> 6;     // 0..7
    const int wr   = wid >> 2;     // 0..1 (64-row band)
    const int wc   = wid & 3;      // 0..3 (32-col band)
    const int wg   = blockIdx.x;
    const int sw   = (wg & 7) * 64 + (wg >> 3);
    const int row0 = (sw >> 2) * 128;
    const int col0 = (sw & 3) * 128;
    const int srow   = lane >> 3;
    const int pchunk = lane & 7;

    f32x4 acc[4][2];
#pragma unroll
    for (int m = 0; m < 4; m++)
#pragma unroll
        for (int n = 0; n < 2; n++) acc[m][n] = {0.f, 0.f, 0.f, 0.f};

    const int NT = K >> 6;

    auto STAGE = [&](int buf, int k0) {
#pragma unroll
        for (int i = 0; i < 2; ++i) {
            const int s   = wid * 2 + i;
            const int row = s * 8 + srow;
            const int lc  = pchunk ^ (row & 7);
            gload16(A  + (size_t)(row0 + row) * K + k0 + lc * 8, &As[buf][s * 512]);
        }
#pragma unroll
        for (int i = 0; i < 2; ++i) {
            const int s   = wid * 2 + i;
            const int row = s * 8 + srow;
            const int lc  = pchunk ^ (row & 7);
            gload16(Wb + (size_t)(col0 + row) * K + k0 + lc * 8, &Bs[buf][s * 512]);
        }
    };

    STAGE(0, 0);
    if (NT > 1) STAGE(1, 64);
    for (int kt = 0; kt < NT; ++kt) {
        const int b = kt & 1;
        if (kt + 1 < NT) {
            asm volatile("s_waitcnt vmcnt(4)" ::: "memory");
        } else {
            asm volatile("s_waitcnt vmcnt(0)" ::: "memory");
        }
        __builtin_amdgcn_s_barrier();
        asm volatile("" ::: "memory");
        short8v aF[2][4], bF[2][2];
#pragma unroll
        for (int ks = 0; ks < 2; ks++) {
            const int k8 = ks * 4 + (lane >> 4);
#pragma unroll
            for (int m = 0; m < 4; m++) {
                const int row = wr * 64 + m * 16 + (lane & 15);
                aF[ks][m] = *(const short8v*)(&As[b][row * 64 + ((k8 ^ (row & 7)) * 8)]);
            }
#pragma unroll
            for (int n = 0; n < 2; n++) {
                const int row = wc * 32 + n * 16 + (lane & 15);
                bF[ks][n] = *(const short8v*)(&Bs[b][row * 64 + ((k8 ^ (row & 7)) * 8)]);
            }
        }
        asm volatile("s_waitcnt lgkmcnt(0)" ::: "memory");
        __builtin_amdgcn_s_barrier();
        asm volatile("" ::: "memory");
        if (kt + 2 < NT) STAGE(b, (kt + 2) << 6);
#pragma unroll
        for (int ks = 0; ks < 2; ks++)
#pragma unroll
            for (int m = 0; m < 4; m++)
#pragma unroll
                for (int n = 0; n < 2; n++)
                    acc[m][n] = __builtin_amdgcn_mfma_f32_16x16x32_bf16(
                        aF[ks][m], bF[ks][n], acc[m][n], 0, 0, 0);
    }

#pragma unroll
    for (int m = 0; m < 4; m++) {
#pragma unroll
        for (int n = 0; n < 2; n++) {
            int colg = col0 + wc * 32 + n * 16 + (lane & 15);
            float bv = bias[colg];
#pragma unroll
            for (int j = 0; j < 4; j++) {
                int rowg = row0 + wr * 64 + m * 16 + ((lane >> 4) * 4) + j;
                size_t off = (size_t)rowg * 512 + colg;
                Coutb[off] = f2bf(acc[m][n][j] + bv + bf2f(xres[off]));
            }
        }
    }
}

// ==== fused LN1 + H: x = bf16(LN(tmpb)); H = bf16(relu(z@W1^T+b1)) ====
// Block = 8 rows (4 waves x 2 rows) + h-phase over 2048 f. z passes
// through 128B of LDS instead of a global round-trip; W1 loads are
// lane-consecutive 16B rows (coalesced); H staged in LDS, b128 stores.
__global__ __launch_bounds__(256) void ln1h_kernel(
    const unsigned short* __restrict__ tmp, unsigned short* __restrict__ x,
    const float* __restrict__ g, const float* __restrict__ b,
    const float* __restrict__ phi,
    const float* __restrict__ W1, const float* __restrict__ b1,
    unsigned short* __restrict__ H) {
    __shared__ float zls[8][4];
    __shared__ unsigned short hls[8 * Ff];
    const int wv   = threadIdx.x >> 6;
    const int lane = threadIdx.x & 63;
    const int rb   = blockIdx.x * 8;
    const int row0 = rb + wv * 2;

    f32x4 g0 = *(const f32x4*)(g + lane * 4);
    f32x4 b0 = *(const f32x4*)(b + lane * 4);
    f32x4 g1 = *(const f32x4*)(g + 256 + lane * 4);
    f32x4 b1v = *(const f32x4*)(b + 256 + lane * 4);

    f32x4 vA0, vA1, vB0, vB1;
    {
        const unsigned short* t0 = tmp + (size_t)row0 * Ee;
        const unsigned short* t1 = tmp + (size_t)(row0 + 1) * Ee;
        ushort4 a0 = *(const ushort4*)(t0 + lane * 4);
        ushort4 a1 = *(const ushort4*)(t0 + 256 + lane * 4);
        ushort4 c0 = *(const ushort4*)(t1 + lane * 4);
        ushort4 c1 = *(const ushort4*)(t1 + 256 + lane * 4);
        vA0 = {bf2f(a0.x), bf2f(a0.y), bf2f(a0.z), bf2f(a0.w)};
        vA1 = {bf2f(a1.x), bf2f(a1.y), bf2f(a1.z), bf2f(a1.w)};
        vB0 = {bf2f(c0.x), bf2f(c0.y), bf2f(c0.z), bf2f(c0.w)};
        vB1 = {bf2f(c1.x), bf2f(c1.y), bf2f(c1.z), bf2f(c1.w)};
    }
    float s0 = vA0.x + vA0.y + vA0.z + vA0.w + vA1.x + vA1.y + vA1.z + vA1.w;
    float s1 = vB0.x + vB0.y + vB0.z + vB0.w + vB1.x + vB1.y + vB1.z + vB1.w;
#pragma unroll
    for (int o = 32; o; o >>= 1) {
        s0 += __shfl_xor(s0, o);
        s1 += __shfl_xor(s1, o);
    }
    float mu0 = s0 * (1.f / 512.f), mu1 = s1 * (1.f / 512.f);
    f32x4 dA0 = {vA0.x - mu0, vA0.y - mu0, vA0.z - mu0, vA0.w - mu0};
    f32x4 dA1 = {vA1.x - mu0, vA1.y - mu0, vA1.z - mu0, vA1.w - mu0};
    f32x4 dB0 = {vB0.x - mu1, vB0.y - mu1, vB0.z - mu1, vB0.w - mu1};
    f32x4 dB1 = {vB1.x - mu1, vB1.y - mu1, vB1.z - mu1, vB1.w - mu1};
    float q0 = dA0.x * dA0.x + dA0.y * dA0.y + dA0.z * dA0.z + dA0.w * dA0.w +
               dA1.x * dA1.x + dA1.y * dA1.y + dA1.z * dA1.z + dA1.w * dA1.w;
    float q1 = dB0.x * dB0.x + dB0.y * dB0.y + dB0.z * dB0.z + dB0.w * dB0.w +
               dB1.x * dB1.x + dB1.y * dB1.y + dB1.z * dB1.z + dB1.w * dB1.w;
#pragma unroll
    for (int o = 32; o; o >>= 1) {
        q0 += __shfl_xor(q0, o);
        q1 += __shfl_xor(q1, o);
    }
    float rs0 = rsqrtf(q0 * (1.f / 512.f) + LN_EPS);
    float rs1 = rsqrtf(q1 * (1.f / 512.f) + LN_EPS);

    f32x4 oA0 = {dA0.x * rs0 * g0.x + b0.x, dA0.y * rs0 * g0.y + b0.y,
                 dA0.z * rs0 * g0.z + b0.z, dA0.w * rs0 * g0.w + b0.w};
    f32x4 oA1 = {dA1.x * rs0 * g1.x + b1v.x, dA1.y * rs0 * g1.y + b1v.y,
                 dA1.z * rs0 * g1.z + b1v.z, dA1.w * rs0 * g1.w + b1v.w};
    f32x4 oB0 = {dB0.x * rs1 * g0.x + b0.x, dB0.y * rs1 * g0.y + b0.y,
                 dB0.z * rs1 * g0.z + b0.z, dB0.w * rs1 * g0.w + b0.w};
    f32x4 oB1 = {dB1.x * rs1 * g1.x + b1v.x, dB1.y * rs1 * g1.y + b1v.y,
                 dB1.z * rs1 * g1.z + b1v.z, dB1.w * rs1 * g1.w + b1v.w};
    ushort4 xA0 = {f2bf(oA0.x), f2bf(oA0.y), f2bf(oA0.z), f2bf(oA0.w)};
    ushort4 xA1 = {f2bf(oA1.x), f2bf(oA1.y), f2bf(oA1.z), f2bf(oA1.w)};
    ushort4 xB0 = {f2bf(oB0.x), f2bf(oB0.y), f2bf(oB0.z), f2bf(oB0.w)};
    ushort4 xB1 = {f2bf(oB1.x), f2bf(oB1.y), f2bf(oB1.z), f2bf(oB1.w)};
    *(ushort4*)(x + (size_t)row0 * Ee + lane * 4) = xA0;
    *(ushort4*)(x + (size_t)row0 * Ee + 256 + lane * 4) = xA1;
    *(ushort4*)(x + (size_t)(row0 + 1) * Ee + lane * 4) = xB0;
    *(ushort4*)(x + (size_t)(row0 + 1) * Ee + 256 + lane * 4) = xB1;
    if (lane == 0) {
        float c0p = fastcos(phi[0]), c1p = fastcos(phi[1]);
        float c2p = fastcos(phi[2]), c3p = fastcos(phi[3]);
        zls[wv * 2][0] = fastcos(oA0.x) * c0p;
        zls[wv * 2][1] = fastcos(oA0.y) * c1p;
        zls[wv * 2][2] = fastcos(oA0.z) * c2p;
        zls[wv * 2][3] = fastcos(oA0.w) * c3p;
        zls[wv * 2 + 1][0] = fastcos(oB0.x) * c0p;
        zls[wv * 2 + 1][1] = fastcos(oB0.y) * c1p;
        zls[wv * 2 + 1][2] = fastcos(oB0.z) * c2p;
        zls[wv * 2 + 1][3] = fastcos(oB0.w) * c3p;
    }
    __syncthreads();

    // ---- h phase: H[rb..rb+7][:] = bf16(relu(z @ W1^T + b1)) ----
    const int t = threadIdx.x;
    f32x4 zr[8];
#pragma unroll
    for (int r = 0; r < 8; ++r)
        zr[r] = *(const f32x4*)(&zls[r][0]);   // LDS broadcast
#pragma unroll
    for (int j = 0; j < 8; ++j) {
        const int f = t + 256 * j;
        f32x4 w = *(const f32x4*)(W1 + (size_t)f * 4);  // coalesced
        float bb = b1[f];                               // coalesced
#pragma unroll
        for (int r = 0; r < 8; ++r) {
            float v = zr[r].x * w.x + zr[r].y * w.y + zr[r].z * w.z +
                      zr[r].w * w.w + bb;
            hls[r * Ff + f] = f2bf(fmaxf(v, 0.f));
        }
    }
    __syncthreads();
#pragma unroll
    for (int j = 0; j < 8; ++j) {
        const int idx = (j * 256 + t) * 8;   // ushort index, 16B per thread
        *(short8v*)(H + (size_t)rb * Ff + idx) = *(const short8v*)(&hls[idx]);
    }
}

// -- LN2: 2 rows per wave on bf16 tmp -> bf16 x; Acos fusion --
__global__ __launch_bounds__(256) void ln_fused(
    const unsigned short* __restrict__ tmp, unsigned short* __restrict__ x,
    const float* __restrict__ g, const float* __restrict__ b,
    const float* __restrict__ theta, unsigned short* __restrict__ acos) {
    const int wv   = threadIdx.x >> 6;
    const int lane = threadIdx.x & 63;
    const int row0 = blockIdx.x * 8 + wv * 2;

    f32x4 g0 = *(const f32x4*)(g + lane * 4);
    f32x4 b0 = *(const f32x4*)(b + lane * 4);
    f32x4 g1 = *(const f32x4*)(g + 256 + lane * 4);
    f32x4 b1v = *(const f32x4*)(b + 256 + lane * 4);

    f32x4 vA0, vA1, vB0, vB1;
    {
        const unsigned short* t0 = tmp + (size_t)row0 * Ee;
        const unsigned short* t1 = tmp + (size_t)(row0 + 1) * Ee;
        ushort4 a0 = *(const ushort4*)(t0 + lane * 4);
        ushort4 a1 = *(const ushort4*)(t0 + 256 + lane * 4);
        ushort4 c0 = *(const ushort4*)(t1 + lane * 4);
        ushort4 c1 = *(const ushort4*)(t1 + 256 + lane * 4);
        vA0 = {bf2f(a0.x), bf2f(a0.y), bf2f(a0.z), bf2f(a0.w)};
        vA1 = {bf2f(a1.x), bf2f(a1.y), bf2f(a1.z), bf2f(a1.w)};
        vB0 = {bf2f(c0.x), bf2f(c0.y), bf2f(c0.z), bf2f(c0.w)};
        vB1 = {bf2f(c1.x), bf2f(c1.y), bf2f(c1.z), bf2f(c1.w)};
    }
    float s0 = vA0.x + vA0.y + vA0.z + vA0.w + vA1.x + vA1.y + vA1.z + vA1.w;
    float s1 = vB0.x + vB0.y + vB0.z + vB0.w + vB1.x + vB1.y + vB1.z + vB1.w;
#pragma unroll
    for (int o = 32; o; o >>= 1) {
        s0 += __shfl_xor(s0, o);
        s1 += __shfl_xor(s1, o);
    }
    float mu0 = s0 * (1.f / 512.f), mu1 = s1 * (1.f / 512.f);
    f32x4 dA0 = {vA0.x - mu0, vA0.y - mu0, vA0.z - mu0, vA0.w - mu0};
    f32x4 dA1 = {vA1.x - mu0, vA1.y - mu0, vA1.z - mu0, vA1.w - mu0};
    f32x4 dB0 = {vB0.x - mu1, vB0.y - mu1, vB0.z - mu1, vB0.w - mu1};
    f32x4 dB1 = {vB1.x - mu1, vB1.y - mu1, vB1.z - mu1, vB1.w - mu1};
    float q0 = dA0.x * dA0.x + dA0.y * dA0.y + dA0.z * dA0.z + dA0.w * dA0.w +
               dA1.x * dA1.x + dA1.y * dA1.y + dA1.z * dA1.z + dA1.w * dA1.w;
    float q1 = dB0.x * dB0.x + dB0.y * dB0.y + dB0.z * dB0.z + dB0.w * dB0.w +
               dB1.x * dB1.x + dB1.y * dB1.y + dB1.z * dB1.z + dB1.w * dB1.w;
#pragma unroll
    for (int o = 32; o; o >>= 1) {
        q0 += __shfl_xor(q0, o);
        q1 += __shfl_xor(q1, o);
    }
    float rs0 = rsqrtf(q0 * (1.f / 512.f) + LN_EPS);
    float rs1 = rsqrtf(q1 * (1.f / 512.f) + LN_EPS);

    f32x4 oA0 = {dA0.x * rs0 * g0.x + b0.x, dA0.y * rs0 * g0.y + b0.y,
                 dA0.z * rs0 * g0.z + b0.z, dA0.w * rs0 * g0.w + b0.w};
    f32x4 oA1 = {dA1.x * rs0 * g1.x + b1v.x, dA1.y * rs0 * g1.y + b1v.y,
                 dA1.z * rs0 * g1.z + b1v.z, dA1.w * rs0 * g1.w + b1v.w};
    f32x4 oB0 = {dB0.x * rs1 * g0.x + b0.x, dB0.y * rs1 * g0.y + b0.y,
                 dB0.z * rs1 * g0.z + b0.z, dB0.w * rs1 * g0.w + b0.w};
    f32x4 oB1 = {dB1.x * rs1 * g1.x + b1v.x, dB1.y * rs1 * g1.y + b1v.y,
                 dB1.z * rs1 * g1.z + b1v.z, dB1.w * rs1 * g1.w + b1v.w};
    ushort4 xA0 = {f2bf(oA0.x), f2bf(oA0.y), f2bf(oA0.z), f2bf(oA0.w)};
    ushort4 xA1 = {f2bf(oA1.x), f2bf(oA1.y), f2bf(oA1.z), f2bf(oA1.w)};
    ushort4 xB0 = {f2bf(oB0.x), f2bf(oB0.y), f2bf(oB0.z), f2bf(oB0.w)};
    ushort4 xB1 = {f2bf(oB1.x), f2bf(oB1.y), f2bf(oB1.z), f2bf(oB1.w)};
    *(ushort4*)(x + (size_t)row0 * Ee + lane * 4) = xA0;
    *(ushort4*)(x + (size_t)row0 * Ee + 256 + lane * 4) = xA1;
    *(ushort4*)(x + (size_t)(row0 + 1) * Ee + lane * 4) = xB0;
    *(ushort4*)(x + (size_t)(row0 + 1) * Ee + 256 + lane * 4) = xB1;
    if (acos != nullptr) {
        f32x4 t0 = *(const f32x4*)(theta + lane * 4);
        f32x4 t1 = *(const f32x4*)(theta + 256 + lane * 4);
        ushort4 cA0, cA1, cB0, cB1;
        cA0.x = f2bf(fastcos(oA0.x + t0.x));
        cA0.y = f2bf(fastcos(oA0.y + t0.y));
        cA0.z = f2bf(fastcos(oA0.z + t0.z));
        cA0.w = f2bf(fastcos(oA0.w + t0.w));
        cA1.x = f2bf(fastcos(oA1.x + t1.x));
        cA1.y = f2bf(fastcos(oA1.y + t1.y));
        cA1.z = f2bf(fastcos(oA1.z + t1.z));
        cA1.w = f2bf(fastcos(oA1.w + t1.w));
        cB0.x = f2bf(fastcos(oB0.x + t0.x));
        cB0.y = f2bf(fastcos(oB0.y + t0.y));
        cB0.z = f2bf(fastcos(oB0.z + t0.z));
        cB0.w = f2bf(fastcos(oB0.w + t0.w));
        cB1.x = f2bf(fastcos(oB1.x + t1.x));
        cB1.y = f2bf(fastcos(oB1.y + t1.y));
        cB1.z = f2bf(fastcos(oB1.z + t1.z));
        cB1.w = f2bf(fastcos(oB1.w + t1.w));
        *(ushort4*)(acos + (size_t)row0 * Ee + lane * 4) = cA0;
        *(ushort4*)(acos + (size_t)row0 * Ee + 256 + lane * 4) = cA1;
        *(ushort4*)(acos + (size_t)(row0 + 1) * Ee + lane * 4) = cB0;
        *(ushort4*)(acos + (size_t)(row0 + 1) * Ee + 256 + lane * 4) = cB1;
    }
}

// ------- parallel pool (bf16 x): partial sums over 64-row chunks -------
__global__ __launch_bounds__(256) void pool_part(const unsigned short* __restrict__ x,
                                                 float* __restrict__ part) {
    int bidx = blockIdx.x, ch = blockIdx.y;
    int t = threadIdx.x;
    float s0 = 0.f, s1 = 0.f;
    for (int s = 0; s < 64; ++s) {
        const unsigned short* row = x + ((size_t)bidx * Ss + ch * 64 + s) * Ee;
        s0 += bf2f(row[t]);
        s1 += bf2f(row[t + 256]);
    }
    float* pr = part + ((size_t)(bidx * 32 + ch)) * Ee;
    pr[t] = s0;
    pr[t + 256] = s1;
}

// ---------------- finish pool + classifier ----------------
__global__ __launch_bounds__(256) void cls_kernel(const float* __restrict__ part,
                                                  const float* __restrict__ clsW,
                                                  const float* __restrict__ clsb,
                                                  float* __restrict__ out) {
    int bidx = blockIdx.x;
    int t = threadIdx.x;
    float p0 = 0.f, p1 = 0.f;
    for (int ch = 0; ch < 32; ++ch) {
        const float* pr = part + ((size_t)(bidx * 32 + ch)) * Ee;
        p0 += pr[t];
        p1 += pr[t + 256];
    }
    p0 *= (1.f / float(Ss));
    p1 *= (1.f / float(Ss));
    __shared__ float red[256];
    for (int c = 0; c < Cc; ++c) {
        red[t] = p0 * clsW[(size_t)c * Ee + t] + p1 * clsW[(size_t)c * Ee + t + 256];
        __syncthreads();
        for (int s2 = 128; s2 > 0; s2 >>= 1) {
            if (t < s2) red[t] += red[t + s2];
            __syncthreads();
        }
        if (t == 0) out[bidx * Cc + c] = red[0] + clsb[c];
        __syncthreads();
    }
}

extern "C" void kernel_launch(void* const* d_in, const int* in_sizes, int n_in,
                              void* d_out, int out_size, void* d_ws, size_t ws_size,
                              hipStream_t stream) {
    const int*   tokens     = (const int*)d_in[0];
    const float* emb        = (const float*)d_in[1];
    const float* theta_attn = (const float*)d_in[2];
    const float* combine_W  = (const float*)d_in[3];
    const float* combine_b  = (const float*)d_in[4];
    const float* ln1_g      = (const float*)d_in[5];
    const float* ln1_b      = (const float*)d_in[6];
    const float* phi_ffn    = (const float*)d_in[7];
    const float* lin1_W     = (const float*)d_in[8];
    const float* lin1_b     = (const float*)d_in[9];
    const float* lin2_W     = (const float*)d_in[10];
    const float* lin2_b     = (const float*)d_in[11];
    const float* ln2_g      = (const float*)d_in[12];
    const float* ln2_b      = (const float*)d_in[13];
    const float* cls_W      = (const float*)d_in[14];
    const float* cls_b      = (const float*)d_in[15];
    float* out = (float*)d_out;

    unsigned short* x    = (unsigned short*)d_ws;            // 16MB bf16
    unsigned short* tmpb = x + (size_t)Nn * Ee;              // 16MB bf16
    float* part = (float*)(tmpb + (size_t)Nn * Ee);          // 512KB
    unsigned short* Wcb  = (unsigned short*)(part + (size_t)Bb * 32 * Ee); // 3MB
    unsigned short* W2b  = Wcb + (size_t)Ll * Ee * Ee;                     // 12MB
    unsigned short* acos = W2b + (size_t)Ll * Ee * Ff;                     // 16MB
    unsigned short* H    = acos + (size_t)Nn * Ee;                         // 64MB
    float* pe = (float*)H;  // overlay: pe (4MB) only used before first ln1h

    {
        int total = Ss * (Ee / 2);
        pe_kernel<<<(total + 255) / 256, 256, 0, stream>>>(pe);
    }
    {
        int total = Nn * Ee / 4;
        embed_kernel<<<(total + 255) / 256, 256, 0, stream>>>(
            tokens, emb, pe, theta_attn, x, acos);
    }
    {
        int n4c = Ll * Ee * Ee / 4;
        cvt_bf16<<<(n4c + 255) / 256, 256, 0, stream>>>(combine_W, Wcb, n4c);
        int n42 = Ll * Ee * Ff / 4;
        cvt_bf16<<<(n42 + 255) / 256, 256, 0, stream>>>(lin2_W, W2b, n42);
    }

    const int ngemm = (Nn / 128) * (Ee / 128);  // 512 blocks, 1D + swizzle
    for (int l = 0; l < Ll; l++) {
        const unsigned short* cWl = Wcb + (size_t)l * Ee * Ee;
        const float* cbl  = combine_b + (size_t)l * Ee;
        const float* g1   = ln1_g + (size_t)l * Ee;
        const float* b1n  = ln1_b + (size_t)l * Ee;
        const float* phil = phi_ffn + (size_t)l * 4;
        const float* w1l  = lin1_W + (size_t)l * Ff * 4;
        const float* b1l  = lin1_b + (size_t)l * Ff;
        const unsigned short* w2l = W2b + (size_t)l * Ee * Ff;
        const float* b2l  = lin2_b + (size_t)l * Ee;
        const float* g2   = ln2_g + (size_t)l * Ee;
        const float* b2n  = ln2_b + (size_t)l * Ee;
        const float* thn  = (l + 1 < Ll) ? theta_attn + (size_t)(l + 1) * Ee : nullptr;
        unsigned short* acn = (l + 1 < Ll) ? acos : nullptr;

        // tmpb = bf16(x + Acos @ Wc^T + cb)
        gemm_bf16<<<ngemm, 512, 0, stream>>>(acos, cWl, cbl, x, tmpb, Ee);
        // x = bf16(LN(tmpb)); H = bf16(relu(cos(x[:,:4])cos(phi) @ W1^T + b1))
        ln1h_kernel<<<Nn / 8, 256, 0, stream>>>(tmpb, x, g1, b1n, phil,
                                                w1l, b1l, H);
        // tmpb = bf16(x + H @ W2^T + b2)
        gemm_bf16<<<ngemm, 512, 0, stream>>>(H, w2l, b2l, x, tmpb, Ff);
        // x = bf16(LN(tmpb)); Acos = bf16(cos(LN + theta_{l+1}))
        ln_fused<<<Nn / 8, 256, 0, stream>>>(tmpb, x, g2, b2n, thn, acn);
    }

    pool_part<<<dim3(Bb, 32), 256, 0, stream>>>(x, part);
    cls_kernel<<<Bb, 256, 0, stream>>>(part, cls_W, cls_b, out);
}

// Round 17
// 586.182 us; speedup vs baseline: 1.1257x; 1.0107x over previous
//
#include <hip/hip_runtime.h>
#include <hip/hip_bf16.h>
#include <math.h>

#define LN_EPS 1e-5f

constexpr int Bb = 8, Ss = 2048, Ee = 512, Ll = 6, Ff = 2048, Cc = 10;
constexpr int Nn = Bb * Ss;  // 16384 rows

typedef __attribute__((ext_vector_type(8))) short short8v;
typedef __attribute__((ext_vector_type(4))) float f32x4;

__device__ __forceinline__ unsigned short f2bf(float f) {
    unsigned int b = __float_as_uint(f);
    b += 0x7FFFu + ((b >> 16) & 1u);   // RNE
    return (unsigned short)(b >> 16);
}

__device__ __forceinline__ float bf2f(unsigned short u) {
    return __uint_as_float((unsigned int)u << 16);
}

__device__ __forceinline__ float fastcos(float x) {
    float r = x * 0.15915494309189535f;     // radians -> revolutions
    r = __builtin_amdgcn_fractf(r);         // reduce to [0,1)
    return __builtin_amdgcn_cosf(r);        // v_cos_f32
}

// async global->LDS, 16B per lane. LDS dest = wave-uniform base + lane*16.
__device__ __forceinline__ void gload16(const void* g, void* lds) {
    __builtin_amdgcn_global_load_lds(
        (__attribute__((address_space(1))) void*)(g),
        (__attribute__((address_space(3))) void*)(lds),
        16, 0, 0);
}

// ---------------- positional encoding table ----------------
__global__ void pe_kernel(float* __restrict__ pe) {
    int p = blockIdx.x * blockDim.x + threadIdx.x;
    int total = Ss * (Ee / 2);
    if (p >= total) return;
    int s = p / (Ee / 2);
    int i = p % (Ee / 2);
    float div = expf(float(2 * i) * (-logf(10000.0f) / float(Ee)));
    float ang = float(s) * div;
    pe[s * Ee + 2 * i]     = sinf(ang);
    pe[s * Ee + 2 * i + 1] = cosf(ang);
}

// ------- embedding + PE -> x (bf16) + Acos for layer 0 -------
__global__ void embed_kernel(const int* __restrict__ tokens,
                             const float* __restrict__ emb,
                             const float* __restrict__ pe,
                             const float* __restrict__ theta0,
                             unsigned short* __restrict__ x,
                             unsigned short* __restrict__ acos) {
    int idx = blockIdx.x * blockDim.x + threadIdx.x;
    int total = Nn * Ee / 4;
    if (idx >= total) return;
    int n  = idx / (Ee / 4);
    int e4 = idx % (Ee / 4);
    int tok = tokens[n];
    int s = n % Ss;
    f32x4 a = *(const f32x4*)(emb + (size_t)tok * Ee + e4 * 4);
    f32x4 p = *(const f32x4*)(pe + (size_t)s * Ee + e4 * 4);
    f32x4 o = a + p;
    ushort4 xo;
    xo.x = f2bf(o.x); xo.y = f2bf(o.y); xo.z = f2bf(o.z); xo.w = f2bf(o.w);
    *(ushort4*)(x + (size_t)n * Ee + e4 * 4) = xo;
    f32x4 t = *(const f32x4*)(theta0 + e4 * 4);
    ushort4 c;
    c.x = f2bf(fastcos(o.x + t.x));
    c.y = f2bf(fastcos(o.y + t.y));
    c.z = f2bf(fastcos(o.z + t.z));
    c.w = f2bf(fastcos(o.w + t.w));
    *(ushort4*)(acos + (size_t)n * Ee + e4 * 4) = c;
}

// ---------------- fp32 -> bf16 weight conversion ----------------
__global__ void cvt_bf16(const float* __restrict__ in,
                         unsigned short* __restrict__ out, int n4) {
    int i = blockIdx.x * blockDim.x + threadIdx.x;
    if (i >= n4) return;
    f32x4 v = *(const f32x4*)(in + (size_t)i * 4);
    ushort4 o;
    o.x = f2bf(v.x); o.y = f2bf(v.y); o.z = f2bf(v.z); o.w = f2bf(v.w);
    *(ushort4*)(out + (size_t)i * 4) = o;
}

// ==== bf16 GEMM: Coutb = bf16(A @ Wb^T + bias + xres), xres bf16 ====
// Round-13 structure (best): 128x128 tile, BK=64, 8 waves, depth-2
// prefetch over 2 LDS buffers via reg-hoisted fragments.
__global__ __launch_bounds__(512, 4) void gemm_bf16(
    const unsigned short* __restrict__ A,
    const unsigned short* __restrict__ Wb,
    const float* __restrict__ bias,
    const unsigned short* __restrict__ xres,
    unsigned short* __restrict__ Coutb,
    int K) {
    __shared__ unsigned short As[2][128 * 64];
    __shared__ unsigned short Bs[2][128 * 64];
    const int tid  = threadIdx.x;
    const int lane = tid & 63;
    const int wid  = tid >> 6;     // 0..7
    const int wr   = wid >> 2;     // 0..1 (64-row band)
    const int wc   = wid & 3;      // 0..3 (32-col band)
    const int wg   = blockIdx.x;
    const int sw   = (wg & 7) * 64 + (wg >> 3);
    const int row0 = (sw >> 2) * 128;
    const int col0 = (sw & 3) * 128;
    const int srow   = lane >> 3;
    const int pchunk = lane & 7;

    f32x4 acc[4][2];
#pragma unroll
    for (int m = 0; m < 4; m++)
#pragma unroll
        for (int n = 0; n < 2; n++) acc[m][n] = {0.f, 0.f, 0.f, 0.f};

    const int NT = K >> 6;

    auto STAGE = [&](int buf, int k0) {
#pragma unroll
        for (int i = 0; i < 2; ++i) {
            const int s   = wid * 2 + i;
            const int row = s * 8 + srow;
            const int lc  = pchunk ^ (row & 7);
            gload16(A  + (size_t)(row0 + row) * K + k0 + lc * 8, &As[buf][s * 512]);
        }
#pragma unroll
        for (int i = 0; i < 2; ++i) {
            const int s   = wid * 2 + i;
            const int row = s * 8 + srow;
            const int lc  = pchunk ^ (row & 7);
            gload16(Wb + (size_t)(col0 + row) * K + k0 + lc * 8, &Bs[buf][s * 512]);
        }
    };

    STAGE(0, 0);
    if (NT > 1) STAGE(1, 64);
    for (int kt = 0; kt < NT; ++kt) {
        const int b = kt & 1;
        if (kt + 1 < NT) {
            asm volatile("s_waitcnt vmcnt(4)" ::: "memory");
        } else {
            asm volatile("s_waitcnt vmcnt(0)" ::: "memory");
        }
        __builtin_amdgcn_s_barrier();
        asm volatile("" ::: "memory");
        short8v aF[2][4], bF[2][2];
#pragma unroll
        for (int ks = 0; ks < 2; ks++) {
            const int k8 = ks * 4 + (lane >> 4);
#pragma unroll
            for (int m = 0; m < 4; m++) {
                const int row = wr * 64 + m * 16 + (lane & 15);
                aF[ks][m] = *(const short8v*)(&As[b][row * 64 + ((k8 ^ (row & 7)) * 8)]);
            }
#pragma unroll
            for (int n = 0; n < 2; n++) {
                const int row = wc * 32 + n * 16 + (lane & 15);
                bF[ks][n] = *(const short8v*)(&Bs[b][row * 64 + ((k8 ^ (row & 7)) * 8)]);
            }
        }
        asm volatile("s_waitcnt lgkmcnt(0)" ::: "memory");
        __builtin_amdgcn_s_barrier();
        asm volatile("" ::: "memory");
        if (kt + 2 < NT) STAGE(b, (kt + 2) << 6);
#pragma unroll
        for (int ks = 0; ks < 2; ks++)
#pragma unroll
            for (int m = 0; m < 4; m++)
#pragma unroll
                for (int n = 0; n < 2; n++)
                    acc[m][n] = __builtin_amdgcn_mfma_f32_16x16x32_bf16(
                        aF[ks][m], bF[ks][n], acc[m][n], 0, 0, 0);
    }

#pragma unroll
    for (int m = 0; m < 4; m++) {
#pragma unroll
        for (int n = 0; n < 2; n++) {
            int colg = col0 + wc * 32 + n * 16 + (lane & 15);
            float bv = bias[colg];
#pragma unroll
            for (int j = 0; j < 4; j++) {
                int rowg = row0 + wr * 64 + m * 16 + ((lane >> 4) * 4) + j;
                size_t off = (size_t)rowg * 512 + colg;
                Coutb[off] = f2bf(acc[m][n][j] + bv + bf2f(xres[off]));
            }
        }
    }
}

// ==== fused LN1 + H: x = bf16(LN(tmpb)); H = bf16(relu(z@W1^T+b1)) ====
// Block = 8 rows (4 waves x 2 rows) + h-phase over 2048 f. z passes
// through 128B of LDS; W1 loads lane-consecutive (coalesced); H staged
// in LDS, b128 stores.
__global__ __launch_bounds__(256) void ln1h_kernel(
    const unsigned short* __restrict__ tmp, unsigned short* __restrict__ x,
    const float* __restrict__ g, const float* __restrict__ b,
    const float* __restrict__ phi,
    const float* __restrict__ W1, const float* __restrict__ b1,
    unsigned short* __restrict__ H) {
    __shared__ float zls[8][4];
    __shared__ unsigned short hls[8 * Ff];
    const int wv   = threadIdx.x >> 6;
    const int lane = threadIdx.x & 63;
    const int rb   = blockIdx.x * 8;
    const int row0 = rb + wv * 2;

    f32x4 g0 = *(const f32x4*)(g + lane * 4);
    f32x4 b0 = *(const f32x4*)(b + lane * 4);
    f32x4 g1 = *(const f32x4*)(g + 256 + lane * 4);
    f32x4 b1v = *(const f32x4*)(b + 256 + lane * 4);

    f32x4 vA0, vA1, vB0, vB1;
    {
        const unsigned short* t0 = tmp + (size_t)row0 * Ee;
        const unsigned short* t1 = tmp + (size_t)(row0 + 1) * Ee;
        ushort4 a0 = *(const ushort4*)(t0 + lane * 4);
        ushort4 a1 = *(const ushort4*)(t0 + 256 + lane * 4);
        ushort4 c0 = *(const ushort4*)(t1 + lane * 4);
        ushort4 c1 = *(const ushort4*)(t1 + 256 + lane * 4);
        vA0 = {bf2f(a0.x), bf2f(a0.y), bf2f(a0.z), bf2f(a0.w)};
        vA1 = {bf2f(a1.x), bf2f(a1.y), bf2f(a1.z), bf2f(a1.w)};
        vB0 = {bf2f(c0.x), bf2f(c0.y), bf2f(c0.z), bf2f(c0.w)};
        vB1 = {bf2f(c1.x), bf2f(c1.y), bf2f(c1.z), bf2f(c1.w)};
    }
    float s0 = vA0.x + vA0.y + vA0.z + vA0.w + vA1.x + vA1.y + vA1.z + vA1.w;
    float s1 = vB0.x + vB0.y + vB0.z + vB0.w + vB1.x + vB1.y + vB1.z + vB1.w;
#pragma unroll
    for (int o = 32; o; o >>= 1) {
        s0 += __shfl_xor(s0, o);
        s1 += __shfl_xor(s1, o);
    }
    float mu0 = s0 * (1.f / 512.f), mu1 = s1 * (1.f / 512.f);
    f32x4 dA0 = {vA0.x - mu0, vA0.y - mu0, vA0.z - mu0, vA0.w - mu0};
    f32x4 dA1 = {vA1.x - mu0, vA1.y - mu0, vA1.z - mu0, vA1.w - mu0};
    f32x4 dB0 = {vB0.x - mu1, vB0.y - mu1, vB0.z - mu1, vB0.w - mu1};
    f32x4 dB1 = {vB1.x - mu1, vB1.y - mu1, vB1.z - mu1, vB1.w - mu1};
    float q0 = dA0.x * dA0.x + dA0.y * dA0.y + dA0.z * dA0.z + dA0.w * dA0.w +
               dA1.x * dA1.x + dA1.y * dA1.y + dA1.z * dA1.z + dA1.w * dA1.w;
    float q1 = dB0.x * dB0.x + dB0.y * dB0.y + dB0.z * dB0.z + dB0.w * dB0.w +
               dB1.x * dB1.x + dB1.y * dB1.y + dB1.z * dB1.z + dB1.w * dB1.w;
#pragma unroll
    for (int o = 32; o; o >>= 1) {
        q0 += __shfl_xor(q0, o);
        q1 += __shfl_xor(q1, o);
    }
    float rs0 = rsqrtf(q0 * (1.f / 512.f) + LN_EPS);
    float rs1 = rsqrtf(q1 * (1.f / 512.f) + LN_EPS);

    f32x4 oA0 = {dA0.x * rs0 * g0.x + b0.x, dA0.y * rs0 * g0.y + b0.y,
                 dA0.z * rs0 * g0.z + b0.z, dA0.w * rs0 * g0.w + b0.w};
    f32x4 oA1 = {dA1.x * rs0 * g1.x + b1v.x, dA1.y * rs0 * g1.y + b1v.y,
                 dA1.z * rs0 * g1.z + b1v.z, dA1.w * rs0 * g1.w + b1v.w};
    f32x4 oB0 = {dB0.x * rs1 * g0.x + b0.x, dB0.y * rs1 * g0.y + b0.y,
                 dB0.z * rs1 * g0.z + b0.z, dB0.w * rs1 * g0.w + b0.w};
    f32x4 oB1 = {dB1.x * rs1 * g1.x + b1v.x, dB1.y * rs1 * g1.y + b1v.y,
                 dB1.z * rs1 * g1.z + b1v.z, dB1.w * rs1 * g1.w + b1v.w};
    ushort4 xA0 = {f2bf(oA0.x), f2bf(oA0.y), f2bf(oA0.z), f2bf(oA0.w)};
    ushort4 xA1 = {f2bf(oA1.x), f2bf(oA1.y), f2bf(oA1.z), f2bf(oA1.w)};
    ushort4 xB0 = {f2bf(oB0.x), f2bf(oB0.y), f2bf(oB0.z), f2bf(oB0.w)};
    ushort4 xB1 = {f2bf(oB1.x), f2bf(oB1.y), f2bf(oB1.z), f2bf(oB1.w)};
    *(ushort4*)(x + (size_t)row0 * Ee + lane * 4) = xA0;
    *(ushort4*)(x + (size_t)row0 * Ee + 256 + lane * 4) = xA1;
    *(ushort4*)(x + (size_t)(row0 + 1) * Ee + lane * 4) = xB0;
    *(ushort4*)(x + (size_t)(row0 + 1) * Ee + 256 + lane * 4) = xB1;
    if (lane == 0) {
        float c0p = fastcos(phi[0]), c1p = fastcos(phi[1]);
        float c2p = fastcos(phi[2]), c3p = fastcos(phi[3]);
        zls[wv * 2][0] = fastcos(oA0.x) * c0p;
        zls[wv * 2][1] = fastcos(oA0.y) * c1p;
        zls[wv * 2][2] = fastcos(oA0.z) * c2p;
        zls[wv * 2][3] = fastcos(oA0.w) * c3p;
        zls[wv * 2 + 1][0] = fastcos(oB0.x) * c0p;
        zls[wv * 2 + 1][1] = fastcos(oB0.y) * c1p;
        zls[wv * 2 + 1][2] = fastcos(oB0.z) * c2p;
        zls[wv * 2 + 1][3] = fastcos(oB0.w) * c3p;
    }
    __syncthreads();

    // ---- h phase: H[rb..rb+7][:] = bf16(relu(z @ W1^T + b1)) ----
    const int t = threadIdx.x;
    f32x4 zr[8];
#pragma unroll
    for (int r = 0; r < 8; ++r)
        zr[r] = *(const f32x4*)(&zls[r][0]);   // LDS broadcast
#pragma unroll
    for (int j = 0; j < 8; ++j) {
        const int f = t + 256 * j;
        f32x4 w = *(const f32x4*)(W1 + (size_t)f * 4);  // coalesced
        float bb = b1[f];                               // coalesced
#pragma unroll
        for (int r = 0; r < 8; ++r) {
            float v = zr[r].x * w.x + zr[r].y * w.y + zr[r].z * w.z +
                      zr[r].w * w.w + bb;
            hls[r * Ff + f] = f2bf(fmaxf(v, 0.f));
        }
    }
    __syncthreads();
#pragma unroll
    for (int j = 0; j < 8; ++j) {
        const int idx = (j * 256 + t) * 8;   // ushort index, 16B per thread
        *(short8v*)(H + (size_t)rb * Ff + idx) = *(const short8v*)(&hls[idx]);
    }
}

// -- LN2: 4 rows per wave (16 rows/block) on bf16 tmp -> bf16 x; Acos --
__global__ __launch_bounds__(256) void ln_fused(
    const unsigned short* __restrict__ tmp, unsigned short* __restrict__ x,
    const float* __restrict__ g, const float* __restrict__ b,
    const float* __restrict__ theta, unsigned short* __restrict__ acos) {
    const int wv   = threadIdx.x >> 6;
    const int lane = threadIdx.x & 63;
    const int row0 = blockIdx.x * 16 + wv * 4;

    f32x4 g0 = *(const f32x4*)(g + lane * 4);
    f32x4 b0 = *(const f32x4*)(b + lane * 4);
    f32x4 g1 = *(const f32x4*)(g + 256 + lane * 4);
    f32x4 b1v = *(const f32x4*)(b + 256 + lane * 4);

    f32x4 v0[4], v1[4];
#pragma unroll
    for (int r = 0; r < 4; ++r) {
        const unsigned short* tr = tmp + (size_t)(row0 + r) * Ee;
        ushort4 a0 = *(const ushort4*)(tr + lane * 4);
        ushort4 a1 = *(const ushort4*)(tr + 256 + lane * 4);
        v0[r] = {bf2f(a0.x), bf2f(a0.y), bf2f(a0.z), bf2f(a0.w)};
        v1[r] = {bf2f(a1.x), bf2f(a1.y), bf2f(a1.z), bf2f(a1.w)};
    }
    float s[4];
#pragma unroll
    for (int r = 0; r < 4; ++r)
        s[r] = v0[r].x + v0[r].y + v0[r].z + v0[r].w +
               v1[r].x + v1[r].y + v1[r].z + v1[r].w;
#pragma unroll
    for (int o = 32; o; o >>= 1)
#pragma unroll
        for (int r = 0; r < 4; ++r) s[r] += __shfl_xor(s[r], o);
    f32x4 d0[4], d1[4];
    float q[4];
#pragma unroll
    for (int r = 0; r < 4; ++r) {
        float mu = s[r] * (1.f / 512.f);
        d0[r] = {v0[r].x - mu, v0[r].y - mu, v0[r].z - mu, v0[r].w - mu};
        d1[r] = {v1[r].x - mu, v1[r].y - mu, v1[r].z - mu, v1[r].w - mu};
        q[r] = d0[r].x * d0[r].x + d0[r].y * d0[r].y + d0[r].z * d0[r].z +
               d0[r].w * d0[r].w + d1[r].x * d1[r].x + d1[r].y * d1[r].y +
               d1[r].z * d1[r].z + d1[r].w * d1[r].w;
    }
#pragma unroll
    for (int o = 32; o; o >>= 1)
#pragma unroll
        for (int r = 0; r < 4; ++r) q[r] += __shfl_xor(q[r], o);
#pragma unroll
    for (int r = 0; r < 4; ++r) {
        float rs = rsqrtf(q[r] * (1.f / 512.f) + LN_EPS);
        f32x4 o0 = {d0[r].x * rs * g0.x + b0.x, d0[r].y * rs * g0.y + b0.y,
                    d0[r].z * rs * g0.z + b0.z, d0[r].w * rs * g0.w + b0.w};
        f32x4 o1 = {d1[r].x * rs * g1.x + b1v.x, d1[r].y * rs * g1.y + b1v.y,
                    d1[r].z * rs * g1.z + b1v.z, d1[r].w * rs * g1.w + b1v.w};
        ushort4 x0 = {f2bf(o0.x), f2bf(o0.y), f2bf(o0.z), f2bf(o0.w)};
        ushort4 x1 = {f2bf(o1.x), f2bf(o1.y), f2bf(o1.z), f2bf(o1.w)};
        *(ushort4*)(x + (size_t)(row0 + r) * Ee + lane * 4) = x0;
        *(ushort4*)(x + (size_t)(row0 + r) * Ee + 256 + lane * 4) = x1;
        if (acos != nullptr) {
            f32x4 t0 = *(const f32x4*)(theta + lane * 4);
            f32x4 t1 = *(const f32x4*)(theta + 256 + lane * 4);
            ushort4 c0, c1;
            c0.x = f2bf(fastcos(o0.x + t0.x));
            c0.y = f2bf(fastcos(o0.y + t0.y));
            c0.z = f2bf(fastcos(o0.z + t0.z));
            c0.w = f2bf(fastcos(o0.w + t0.w));
            c1.x = f2bf(fastcos(o1.x + t1.x));
            c1.y = f2bf(fastcos(o1.y + t1.y));
            c1.z = f2bf(fastcos(o1.z + t1.z));
            c1.w = f2bf(fastcos(o1.w + t1.w));
            *(ushort4*)(acos + (size_t)(row0 + r) * Ee + lane * 4) = c0;
            *(ushort4*)(acos + (size_t)(row0 + r) * Ee + 256 + lane * 4) = c1;
        }
    }
}

// -- parallel pool (bf16 x): vectorized short8 loads, LDS cross-reduce --
__global__ __launch_bounds__(256) void pool_part(const unsigned short* __restrict__ x,
                                                 float* __restrict__ part) {
    __shared__ float red[4][512];
    const int bidx = blockIdx.x, ch = blockIdx.y;
    const int t  = threadIdx.x;
    const int cg = t & 63;     // col group: cols 8*cg .. 8*cg+7
    const int rg = t >> 6;     // row group 0..3
    float acc[8] = {};
    for (int s = rg; s < 64; s += 4) {
        const unsigned short* row = x + ((size_t)bidx * Ss + ch * 64 + s) * Ee;
        short8v v = *(const short8v*)(row + cg * 8);
#pragma unroll
        for (int j = 0; j < 8; ++j) acc[j] += bf2f((unsigned short)v[j]);
    }
#pragma unroll
    for (int j = 0; j < 8; ++j) red[rg][cg * 8 + j] = acc[j];
    __syncthreads();
    float s0 = red[0][t] + red[1][t] + red[2][t] + red[3][t];
    float s1 = red[0][t + 256] + red[1][t + 256] + red[2][t + 256] + red[3][t + 256];
    float* pr = part + ((size_t)(bidx * 32 + ch)) * Ee;
    pr[t] = s0;
    pr[t + 256] = s1;
}

// ---------------- finish pool + classifier ----------------
__global__ __launch_bounds__(256) void cls_kernel(const float* __restrict__ part,
                                                  const float* __restrict__ clsW,
                                                  const float* __restrict__ clsb,
                                                  float* __restrict__ out) {
    int bidx = blockIdx.x;
    int t = threadIdx.x;
    float p0 = 0.f, p1 = 0.f;
    for (int ch = 0; ch < 32; ++ch) {
        const float* pr = part + ((size_t)(bidx * 32 + ch)) * Ee;
        p0 += pr[t];
        p1 += pr[t + 256];
    }
    p0 *= (1.f / float(Ss));
    p1 *= (1.f / float(Ss));
    __shared__ float red[256];
    for (int c = 0; c < Cc; ++c) {
        red[t] = p0 * clsW[(size_t)c * Ee + t] + p1 * clsW[(size_t)c * Ee + t + 256];
        __syncthreads();
        for (int s2 = 128; s2 > 0; s2 >>= 1) {
            if (t < s2) red[t] += red[t + s2];
            __syncthreads();
        }
        if (t == 0) out[bidx * Cc + c] = red[0] + clsb[c];
        __syncthreads();
    }
}

extern "C" void kernel_launch(void* const* d_in, const int* in_sizes, int n_in,
                              void* d_out, int out_size, void* d_ws, size_t ws_size,
                              hipStream_t stream) {
    const int*   tokens     = (const int*)d_in[0];
    const float* emb        = (const float*)d_in[1];
    const float* theta_attn = (const float*)d_in[2];
    const float* combine_W  = (const float*)d_in[3];
    const float* combine_b  = (const float*)d_in[4];
    const float* ln1_g      = (const float*)d_in[5];
    const float* ln1_b      = (const float*)d_in[6];
    const float* phi_ffn    = (const float*)d_in[7];
    const float* lin1_W     = (const float*)d_in[8];
    const float* lin1_b     = (const float*)d_in[9];
    const float* lin2_W     = (const float*)d_in[10];
    const float* lin2_b     = (const float*)d_in[11];
    const float* ln2_g      = (const float*)d_in[12];
    const float* ln2_b      = (const float*)d_in[13];
    const float* cls_W      = (const float*)d_in[14];
    const float* cls_b      = (const float*)d_in[15];
    float* out = (float*)d_out;

    unsigned short* x    = (unsigned short*)d_ws;            // 16MB bf16
    unsigned short* tmpb = x + (size_t)Nn * Ee;              // 16MB bf16
    float* part = (float*)(tmpb + (size_t)Nn * Ee);          // 512KB
    unsigned short* Wcb  = (unsigned short*)(part + (size_t)Bb * 32 * Ee); // 3MB
    unsigned short* W2b  = Wcb + (size_t)Ll * Ee * Ee;                     // 12MB
    unsigned short* acos = W2b + (size_t)Ll * Ee * Ff;                     // 16MB
    unsigned short* H    = acos + (size_t)Nn * Ee;                         // 64MB
    float* pe = (float*)H;  // overlay: pe (4MB) only used before first ln1h

    {
        int total = Ss * (Ee / 2);
        pe_kernel<<<(total + 255) / 256, 256, 0, stream>>>(pe);
    }
    {
        int total = Nn * Ee / 4;
        embed_kernel<<<(total + 255) / 256, 256, 0, stream>>>(
            tokens, emb, pe, theta_attn, x, acos);
    }
    {
        int n4c = Ll * Ee * Ee / 4;
        cvt_bf16<<<(n4c + 255) / 256, 256, 0, stream>>>(combine_W, Wcb, n4c);
        int n42 = Ll * Ee * Ff / 4;
        cvt_bf16<<<(n42 + 255) / 256, 256, 0, stream>>>(lin2_W, W2b, n42);
    }

    const int ngemm = (Nn / 128) * (Ee / 128);  // 512 blocks, 1D + swizzle
    for (int l = 0; l < Ll; l++) {
        const unsigned short* cWl = Wcb + (size_t)l * Ee * Ee;
        const float* cbl  = combine_b + (size_t)l * Ee;
        const float* g1   = ln1_g + (size_t)l * Ee;
        const float* b1n  = ln1_b + (size_t)l * Ee;
        const float* phil = phi_ffn + (size_t)l * 4;
        const float* w1l  = lin1_W + (size_t)l * Ff * 4;
        const float* b1l  = lin1_b + (size_t)l * Ff;
        const unsigned short* w2l = W2b + (size_t)l * Ee * Ff;
        const float* b2l  = lin2_b + (size_t)l * Ee;
        const float* g2   = ln2_g + (size_t)l * Ee;
        const float* b2n  = ln2_b + (size_t)l * Ee;
        const float* thn  = (l + 1 < Ll) ? theta_attn + (size_t)(l + 1) * Ee : nullptr;
        unsigned short* acn = (l + 1 < Ll) ? acos : nullptr;

        // tmpb = bf16(x + Acos @ Wc^T + cb)
        gemm_bf16<<<ngemm, 512, 0, stream>>>(acos, cWl, cbl, x, tmpb, Ee);
        // x = bf16(LN(tmpb)); H = bf16(relu(cos(x[:,:4])cos(phi) @ W1^T + b1))
        ln1h_kernel<<<Nn / 8, 256, 0, stream>>>(tmpb, x, g1, b1n, phil,
                                                w1l, b1l, H);
        // tmpb = bf16(x + H @ W2^T + b2)
        gemm_bf16<<<ngemm, 512, 0, stream>>>(H, w2l, b2l, x, tmpb, Ff);
        // x = bf16(LN(tmpb)); Acos = bf16(cos(LN + theta_{l+1}))
        ln_fused<<<Nn / 16, 256, 0, stream>>>(tmpb, x, g2, b2n, thn, acn);
    }

    pool_part<<<dim3(Bb, 32), 256, 0, stream>>>(x, part);
    cls_kernel<<<Bb, 256, 0, stream>>>(part, cls_W, cls_b, out);
}